// Round 3
// baseline (542.913 us; speedup 1.0000x reference)
//
#include <hip/hip_runtime.h>
#include <hip/hip_bf16.h>
#include <math.h>

#define BATCH   4
#define SEQLEN  4096
#define DMODEL  1024
#define DSTATE  16
#define DCONV   4
#define NHEADS  8
#define CHUNKSZ 64
#define DINNER  2048
#define HEADDIM 256          // DINNER / NHEADS
#define CONVDIM 2080         // DINNER + 2*DSTATE
#define DPROJ   4136         // 2*DINNER + 2*DSTATE + NHEADS
#define NPADW   4352         // W_in rows padded to multiple of 256 (17 N-tiles)
#define LDP     4224         // proj row stride (8448 B = 64B-aligned rows)
#define ROWS    (BATCH*SEQLEN)   // 16384
#define NCHUNK  (SEQLEN/CHUNKSZ) // 64

typedef unsigned short bf16_t;
typedef __attribute__((ext_vector_type(8))) short bfrag;   // 8 bf16 = 4 VGPRs
typedef __attribute__((ext_vector_type(4))) float f32x4;

__device__ __forceinline__ float sigmoidf_(float v) { return 1.0f / (1.0f + __expf(-v)); }
__device__ __forceinline__ float siluf_(float v)    { return v * sigmoidf_(v); }
__device__ __forceinline__ float softplusf_(float v) {
    return fmaxf(v, 0.f) + log1pf(__expf(-fabsf(v)));
}

__device__ __forceinline__ float bf2f(bf16_t u) {
    union { unsigned int i; float f; } v; v.i = ((unsigned int)u) << 16; return v.f;
}
__device__ __forceinline__ float bflo(unsigned int u) {
    union { unsigned int i; float f; } v; v.i = u << 16; return v.f;
}
__device__ __forceinline__ float bfhi(unsigned int u) {
    union { unsigned int i; float f; } v; v.i = u & 0xffff0000u; return v.f;
}
__device__ __forceinline__ bf16_t f2bf(float f) {   // round-to-nearest-even
    unsigned int x = __float_as_uint(f);
    unsigned int r = (x + 0x7fffu + ((x >> 16) & 1u)) >> 16;
    return (bf16_t)r;
}
__device__ __forceinline__ unsigned int pack2(float a, float b) {
    return (unsigned int)f2bf(a) | ((unsigned int)f2bf(b) << 16);
}

__device__ __forceinline__ void async_copy16(const bf16_t* g, bf16_t* l) {
    __builtin_amdgcn_global_load_lds(
        (const __attribute__((address_space(1))) void*)g,
        (__attribute__((address_space(3))) void*)l, 16, 0, 0);
}

// counted waits as literal inline asm (m201 style); barrier with compiler fence
#define WAITV(N)  asm volatile("s_waitcnt vmcnt(" #N ")" ::: "memory")
#define LGKM8     asm volatile("s_waitcnt lgkmcnt(8)" ::: "memory")
#define LGKM0                                                                 \
    do { asm volatile("s_waitcnt lgkmcnt(0)" ::: "memory");                   \
         __builtin_amdgcn_sched_barrier(0); } while (0)
__device__ __forceinline__ void barrier_() {
    __builtin_amdgcn_s_barrier();
    asm volatile("" ::: "memory");
}

// ---------------------------------------------------------------------------
// conversion kernels
// ---------------------------------------------------------------------------
__global__ __launch_bounds__(256)
void cvt_f32_bf16(const float* __restrict__ src, bf16_t* __restrict__ dst, int n8)
{
    int i = blockIdx.x * 256 + threadIdx.x;
    if (i >= n8) return;
    float4 a = *(const float4*)&src[(size_t)i * 8];
    float4 b = *(const float4*)&src[(size_t)i * 8 + 4];
    uint4 o;
    o.x = pack2(a.x, a.y); o.y = pack2(a.z, a.w);
    o.z = pack2(b.x, b.y); o.w = pack2(b.z, b.w);
    *(uint4*)&dst[(size_t)i * 8] = o;
}

// W_in (4136x1024) -> bf16 padded to 4352 rows (zeros)
__global__ __launch_bounds__(256)
void cvt_pad_w1(const float* __restrict__ src, bf16_t* __restrict__ dst)
{
    int i = blockIdx.x * 256 + threadIdx.x;
    if (i >= NPADW * DMODEL / 4) return;
    size_t e = (size_t)i * 4;
    int row = (int)(e >> 10);
    ushort4 o = make_ushort4(0, 0, 0, 0);
    if (row < DPROJ) {
        float4 v = *(const float4*)&src[e];
        o.x = f2bf(v.x); o.y = f2bf(v.y); o.z = f2bf(v.z); o.w = f2bf(v.w);
    }
    *(ushort4*)&dst[e] = o;
}

// Wb2[n][k] = bf16(W_out[n][k] * norm_w[k])  — norm folded into the weight
__global__ __launch_bounds__(256)
void cvt_w2(const float* __restrict__ W, const float* __restrict__ norm_w,
            bf16_t* __restrict__ dst)
{
    int i = blockIdx.x * 256 + threadIdx.x;
    if (i >= DMODEL * DINNER / 4) return;
    size_t e = (size_t)i * 4;
    int k = (int)(e & (DINNER - 1));
    float4 v = *(const float4*)&W[e];
    float4 w = *(const float4*)&norm_w[k];
    ushort4 o;
    o.x = f2bf(v.x * w.x); o.y = f2bf(v.y * w.y);
    o.z = f2bf(v.z * w.z); o.w = f2bf(v.w * w.w);
    *(ushort4*)&dst[e] = o;
}

// ---------------------------------------------------------------------------
// 256x256 MFMA GEMM, m201-faithful fine interleave.
// 512 threads = 8 waves (2Mx4N), per-wave 128x64 output, BK=64.
// Per phase: {ds_read this phase's frags | vmcnt gate | staging issue}
//            -> s_barrier -> lgkmcnt(0)+sched_barrier(0)
//            -> setprio(1) 16 MFMA setprio(0) -> s_barrier.
// Reads issue in the PRE-barrier region so their latency drains under the
// previous phase's MFMA tail + barrier skew (the coarse variant exposed it).
// One af + one bf register set still suffices: each set's refill is one full
// MFMA-region after its last use. Staging: slot re-staged right after its
// last read retires globally (Bh0 -> other buf @ph0; Ah0/Bh1/Ah1 -> same buf
// @ph1/ph2/ph3, for tile t+2). vmcnt gates (pre-B1, guarding the NEXT
// phase's reads): ph0=10, ph1=10, ph3=6; never drain-0 except final tiles.
// ---------------------------------------------------------------------------
__device__ __forceinline__
void ld_afrags(bfrag (&af)[4][2], const bf16_t* base, int wmqi, int fr, int quad)
{
    #pragma unroll
    for (int i2 = 0; i2 < 4; ++i2)
        #pragma unroll
        for (int kk = 0; kk < 2; ++kk)
            af[i2][kk] = *(const bfrag*)
                &base[(wmqi + i2*16 + fr)*64 + (((kk*4 + quad) ^ (fr & 7)) * 8)];
}
__device__ __forceinline__
void ld_bfrags(bfrag (&bf_)[2][2], const bf16_t* base, int wnqj, int fr, int quad)
{
    #pragma unroll
    for (int j2 = 0; j2 < 2; ++j2)
        #pragma unroll
        for (int kk = 0; kk < 2; ++kk)
            bf_[j2][kk] = *(const bfrag*)
                &base[(wnqj + j2*16 + fr)*64 + (((kk*4 + quad) ^ (fr & 7)) * 8)];
}
template<int QI, int QJ>
__device__ __forceinline__
void mm8(f32x4 (&acc)[8][4], const bfrag (&af)[4][2], const bfrag (&bf_)[2][2])
{
    __builtin_amdgcn_s_setprio(1);
    #pragma unroll
    for (int i2 = 0; i2 < 4; ++i2)
        #pragma unroll
        for (int j2 = 0; j2 < 2; ++j2)
            #pragma unroll
            for (int kk = 0; kk < 2; ++kk)
                acc[QI*4 + i2][QJ*2 + j2] = __builtin_amdgcn_mfma_f32_16x16x32_bf16(
                    af[i2][kk], bf_[j2][kk], acc[QI*4 + i2][QJ*2 + j2], 0, 0, 0);
    __builtin_amdgcn_s_setprio(0);
}

template<bool OUT_BF16>
__device__ __forceinline__
void gemm256_body(const bf16_t* __restrict__ A, const bf16_t* __restrict__ W,
                  void* __restrict__ Cv, const float* __restrict__ rowScale,
                  int Nstore, int K, int lda, int ldw, int ldc)
{
    __shared__ __align__(16) bf16_t smem[65536];   // 128 KiB
    bf16_t* As = smem;            // [2][256][64]
    bf16_t* Ws = smem + 32768;    // [2][256][64]

    const int tid  = threadIdx.x;
    const int wave = tid >> 6, lane = tid & 63;
    const int quad = lane >> 4, fr = lane & 15;
    const int ln3  = lane >> 3;
    const int cswz = ((lane & 7) ^ ln3) * 8;       // pre-swizzled source column

    const int gx   = gridDim.x;
    const int nwg  = gx * gridDim.y;
    const int flat = blockIdx.y * gx + blockIdx.x;
    const int q8   = nwg >> 3;                     // nwg % 8 == 0 at both call sites
    const int swz  = (flat & 7) * q8 + (flat >> 3);
    const int col0 = (swz % gx) * 256;
    const int row0 = (swz / gx) * 256;

    const int wm = (wave >> 2) * 128, wn = (wave & 3) * 64;

    // staging source pointers: 2 halves x 2 calls each for A and W.
    const bf16_t* gA[2][2];
    const bf16_t* gW[2][2];
    #pragma unroll
    for (int h = 0; h < 2; ++h)
        #pragma unroll
        for (int q = 0; q < 2; ++q) {
            int rA = 128*q + 8*wave + 64*h;
            int rB = 128*q + 64*(wave >> 2) + 8*(wave & 3) + 32*h;
            gA[h][q] = A + (size_t)(row0 + rA + ln3) * lda + cswz;
            gW[h][q] = W + (size_t)(col0 + rB + ln3) * ldw + cswz;
        }

#define STG_A(H, Q, NB, K0S)                                                     \
    async_copy16(gA[H][Q] + (K0S),                                               \
                 &As[(NB)*16384 + (128*(Q) + 8*wave + 64*(H))*64])
#define STG_B(H, Q, NB, K0S)                                                     \
    async_copy16(gW[H][Q] + (K0S),                                               \
                 &Ws[(NB)*16384 + (128*(Q) + 64*(wave>>2) + 8*(wave&3) + 32*(H))*64])

    f32x4 acc[8][4];
    #pragma unroll
    for (int i = 0; i < 8; ++i)
        #pragma unroll
        for (int j = 0; j < 4; ++j) {
            f32x4 z = {0.f, 0.f, 0.f, 0.f};
            acc[i][j] = z;
        }
    bfrag af[4][2], bf_[2][2];

    // prologue: issue order defines vmcnt counting. Tile0 complete in group
    // order [Ah0,Bh1,Ah1,Bh0]; tile1 all but Bh0 (staged at ph0 of t=0).
    STG_A(0,0,0,0);  STG_A(0,1,0,0);
    STG_B(1,0,0,0);  STG_B(1,1,0,0);
    STG_A(1,0,0,0);  STG_A(1,1,0,0);
    STG_B(0,0,0,0);  STG_B(0,1,0,0);
    STG_A(0,0,1,64); STG_A(0,1,1,64);
    STG_B(1,0,1,64); STG_B(1,1,1,64);
    STG_A(1,0,1,64); STG_A(1,1,1,64);
    WAITV(6);            // retire tile0's 8 calls in every wave...
    barrier_();          // ...then globally -> ph0(0) reads are safe

// BUF_: buffer of tile t. SB0_: stage Bh0_{t+1} -> BUF_^1 @ KB0_ (ph0).
// SR_: stage {Ah0,Bh1,Ah1}_{t+2} -> BUF_ @ KR_ (ph1/ph2/ph3).
// V0_/V1_/V3_: vmcnt gates guarding the NEXT phase's reads (pre-B1).
#define TILE_STEP(BUF_, SB0_, KB0_, SR_, KR_, V0_, V1_, V3_) do {                \
    /* ph0: Q(0,0) — reads a0,b0 (12); gate for ph1's b1 */                      \
    ld_afrags(af, &As[(BUF_)*16384], wm, fr, quad);                              \
    ld_bfrags(bf_, &Ws[(BUF_)*16384], wn, fr, quad);                             \
    WAITV(V0_);                                                                  \
    if (SB0_) { STG_B(0,0,(BUF_)^1,KB0_); STG_B(0,1,(BUF_)^1,KB0_); }            \
    LGKM8;                                                                       \
    barrier_(); LGKM0;                                                           \
    mm8<0,0>(acc, af, bf_);                                                      \
    barrier_();                                                                  \
    /* ph1: Q(0,1) — reads b1 (4); gate for ph2's a1 */                          \
    ld_bfrags(bf_, &Ws[(BUF_)*16384], wn + 32, fr, quad);                        \
    WAITV(V1_);                                                                  \
    if (SR_) { STG_A(0,0,BUF_,KR_); STG_A(0,1,BUF_,KR_); }                       \
    barrier_(); LGKM0;                                                           \
    mm8<0,1>(acc, af, bf_);                                                      \
    barrier_();                                                                  \
    /* ph2: Q(1,1) — reads a1 (8); no gate (ph3 re-reads resident b0) */         \
    ld_afrags(af, &As[(BUF_)*16384], wm + 64, fr, quad);                         \
    if (SR_) { STG_B(1,0,BUF_,KR_); STG_B(1,1,BUF_,KR_); }                       \
    barrier_(); LGKM0;                                                           \
    mm8<1,1>(acc, af, bf_);                                                      \
    barrier_();                                                                  \
    /* ph3: Q(1,0) — re-reads b0 (4); gate for next tile's ph0 */                \
    ld_bfrags(bf_, &Ws[(BUF_)*16384], wn, fr, quad);                             \
    if (SR_) { STG_A(1,0,BUF_,KR_); STG_A(1,1,BUF_,KR_); }                       \
    WAITV(V3_);                                                                  \
    barrier_(); LGKM0;                                                           \
    mm8<1,0>(acc, af, bf_);                                                      \
    barrier_();                                                                  \
} while (0)

    const int nt = K >> 6;                         // nt >= 4 at both call sites
    for (int t = 0; t < nt - 2; ++t)
        TILE_STEP((t & 1), 1, (t + 1) * 64, 1, (t + 2) * 64, 10, 10, 6);
    TILE_STEP(((nt - 2) & 1), 1, (nt - 1) * 64, 0, 0, 10, 10, 0);
    TILE_STEP(((nt - 1) & 1), 0, 0, 0, 0, 0, 0, 0);

#undef TILE_STEP
#undef STG_A
#undef STG_B

    if (OUT_BF16) {
        // LDS-staged coalesced epilogue: two 128-row passes through smem[128][264]
        __syncthreads();
        bf16_t* C = (bf16_t*)Cv;
        #pragma unroll
        for (int pass = 0; pass < 2; ++pass) {
            if ((wave >> 2) == pass) {
                #pragma unroll
                for (int i = 0; i < 8; ++i)
                    #pragma unroll
                    for (int j = 0; j < 4; ++j) {
                        int col = wn + 16 * j + fr;
                        #pragma unroll
                        for (int r = 0; r < 4; ++r) {
                            int rl = 16 * i + quad * 4 + r;
                            smem[rl * 264 + col] = f2bf(acc[i][j][r]);
                        }
                    }
            }
            __syncthreads();
            #pragma unroll
            for (int k = 0; k < 8; ++k) {
                int id = k * 512 + tid;
                int rl = id >> 5, ch = id & 31;
                if (col0 + ch * 8 < Nstore) {
                    uint4 v = *(const uint4*)&smem[rl * 264 + ch * 8];
                    *(uint4*)&C[(size_t)(row0 + pass * 128 + rl) * ldc
                                + col0 + ch * 8] = v;
                }
            }
            if (pass == 0) __syncthreads();
        }
    } else {
        // f32 direct stores: 16 lanes x 4B are full 64B lines already
        float rs[8][4];
        #pragma unroll
        for (int i = 0; i < 8; ++i) {
            size_t m = (size_t)row0 + wm + i * 16 + quad * 4;
            #pragma unroll
            for (int r = 0; r < 4; ++r) rs[i][r] = rowScale ? rowScale[m + r] : 1.f;
        }
        float* C = (float*)Cv;
        #pragma unroll
        for (int j = 0; j < 4; ++j) {
            int n = col0 + wn + j * 16 + fr;
            if (n < Nstore) {
                #pragma unroll
                for (int i = 0; i < 8; ++i) {
                    size_t m = (size_t)row0 + wm + i * 16 + quad * 4;
                    #pragma unroll
                    for (int r = 0; r < 4; ++r)
                        C[(m + r) * ldc + n] = acc[i][j][r] * rs[i][r];
                }
            }
        }
    }
}

// distinct names for profiler attribution
__global__ __launch_bounds__(512, 2)
void gemm_g1(const bf16_t* __restrict__ A, const bf16_t* __restrict__ W,
             void* __restrict__ Cv, const float* __restrict__ rowScale,
             int Nstore, int K, int lda, int ldw, int ldc)
{ gemm256_body<true>(A, W, Cv, rowScale, Nstore, K, lda, ldw, ldc); }

__global__ __launch_bounds__(512, 2)
void gemm_g2(const bf16_t* __restrict__ A, const bf16_t* __restrict__ W,
             void* __restrict__ Cv, const float* __restrict__ rowScale,
             int Nstore, int K, int lda, int ldw, int ldc)
{ gemm256_body<false>(A, W, Cv, rowScale, Nstore, K, lda, ldw, ldc); }

// ---------------------------------------------------------------------------
// Fused conv+SSD. One block per (chunk, head, batch), 256 threads.
// (unchanged)
// ---------------------------------------------------------------------------
__global__ __launch_bounds__(256)
void ssd_fused(const bf16_t* __restrict__ proj, const float* __restrict__ conv_w,
               const float* __restrict__ conv_b, const float* __restrict__ dt_bias,
               const float* __restrict__ log_A, const float* __restrict__ D_skip,
               bf16_t* __restrict__ ybuf)
{
    __shared__ float Bc[64][16];
    __shared__ float Cc[64][16];
    __shared__ float Bp[64][16];
    __shared__ float dtc[64];
    __shared__ float dtp[64];
    __shared__ __align__(16) bf16_t sc_b[64][72];   // scores
    __shared__ __align__(16) bf16_t xT[256][72];    // x*dt; reused as Y[64][264]
    __shared__ __align__(16) bf16_t SpT[256][32];   // SpT[p][n], n>=16 zero
    __shared__ __align__(16) bf16_t A2[64][32];     // e(l)*C[l][n], n>=16 zero

    const int c = blockIdx.x, h = blockIdx.y, b = blockIdx.z;
    const int t = threadIdx.x;
    const int row0 = b * SEQLEN + c * CHUNKSZ;
    const float a   = -__expf(log_A[h]);
    const float Dsk = D_skip[h];
    const float bias = dt_bias[h];

    // ---- phase A1: cur-chunk B/C conv+silu (all 256 threads) ----
    {
        int s = t >> 2, ch8 = (t & 3) * 8;      // 8 channels of [0,32)
        int l = c * CHUNKSZ + s;
        const bf16_t* base = &proj[(size_t)(row0 + s) * LDP + 4096 + ch8];
        uint4 zz = make_uint4(0, 0, 0, 0);
        uint4 u3 = *(const uint4*)&base[0];
        uint4 u2 = (l >= 1) ? *(const uint4*)&base[-LDP]     : zz;
        uint4 u1 = (l >= 2) ? *(const uint4*)&base[-2 * LDP] : zz;
        uint4 u0 = (l >= 3) ? *(const uint4*)&base[-3 * LDP] : zz;
        float t3[8] = {bflo(u3.x), bfhi(u3.x), bflo(u3.y), bfhi(u3.y),
                       bflo(u3.z), bfhi(u3.z), bflo(u3.w), bfhi(u3.w)};
        float t2[8] = {bflo(u2.x), bfhi(u2.x), bflo(u2.y), bfhi(u2.y),
                       bflo(u2.z), bfhi(u2.z), bflo(u2.w), bfhi(u2.w)};
        float t1[8] = {bflo(u1.x), bfhi(u1.x), bflo(u1.y), bfhi(u1.y),
                       bflo(u1.z), bfhi(u1.z), bflo(u1.w), bfhi(u1.w)};
        float t0[8] = {bflo(u0.x), bfhi(u0.x), bflo(u0.y), bfhi(u0.y),
                       bflo(u0.z), bfhi(u0.z), bflo(u0.w), bfhi(u0.w)};
        #pragma unroll
        for (int j = 0; j < 8; ++j) {
            int ch = ch8 + j;
            float4 w = *(const float4*)&conv_w[(2048 + ch) * 4];
            float av = conv_b[2048 + ch];
            av = fmaf(w.x, t0[j], av);
            av = fmaf(w.y, t1[j], av);
            av = fmaf(w.z, t2[j], av);
            av = fmaf(w.w, t3[j], av);
            float v = siluf_(av);
            if (ch < 16) Bc[s][ch] = v; else Cc[s][ch - 16] = v;
        }
    }
    // ---- phase A2: prev-chunk B conv (t<128) | dt cur/prev (t>=128) ----
    if (t < 128) {
        int s = t >> 1, ch8 = (t & 1) * 8;      // 8 channels of [0,16)
        float vout[8];
        #pragma unroll
        for (int j = 0; j < 8; ++j) vout[j] = 0.f;
        if (c > 0) {
            int l = (c - 1) * CHUNKSZ + s;
            const bf16_t* base = &proj[(size_t)(row0 - CHUNKSZ + s) * LDP + 4096 + ch8];
            uint4 zz = make_uint4(0, 0, 0, 0);
            uint4 u3 = *(const uint4*)&base[0];
            uint4 u2 = (l >= 1) ? *(const uint4*)&base[-LDP]     : zz;
            uint4 u1 = (l >= 2) ? *(const uint4*)&base[-2 * LDP] : zz;
            uint4 u0 = (l >= 3) ? *(const uint4*)&base[-3 * LDP] : zz;
            float t3[8] = {bflo(u3.x), bfhi(u3.x), bflo(u3.y), bfhi(u3.y),
                           bflo(u3.z), bfhi(u3.z), bflo(u3.w), bfhi(u3.w)};
            float t2[8] = {bflo(u2.x), bfhi(u2.x), bflo(u2.y), bfhi(u2.y),
                           bflo(u2.z), bfhi(u2.z), bflo(u2.w), bfhi(u2.w)};
            float t1[8] = {bflo(u1.x), bfhi(u1.x), bflo(u1.y), bfhi(u1.y),
                           bflo(u1.z), bfhi(u1.z), bflo(u1.w), bfhi(u1.w)};
            float t0[8] = {bflo(u0.x), bfhi(u0.x), bflo(u0.y), bfhi(u0.y),
                           bflo(u0.z), bfhi(u0.z), bflo(u0.w), bfhi(u0.w)};
            #pragma unroll
            for (int j = 0; j < 8; ++j) {
                int ch = ch8 + j;
                float4 w = *(const float4*)&conv_w[(2048 + ch) * 4];
                float av = conv_b[2048 + ch];
                av = fmaf(w.x, t0[j], av);
                av = fmaf(w.y, t1[j], av);
                av = fmaf(w.z, t2[j], av);
                av = fmaf(w.w, t3[j], av);
                vout[j] = siluf_(av);
            }
        }
        #pragma unroll
        for (int j = 0; j < 8; ++j) Bp[s][ch8 + j] = vout[j];
    } else if (t < 192) {
        int s = t - 128;
        float v = bf2f(proj[(size_t)(row0 + s) * LDP + 4128 + h]) + bias;
        dtc[s] = softplusf_(v);
    } else {
        int s = t - 192;
        float w = 0.f;
        if (c > 0) {
            float v = bf2f(proj[(size_t)(row0 - CHUNKSZ + s) * LDP + 4128 + h]) + bias;
            w = softplusf_(v) * __expf(a * (float)(63 - s));   // fold decay_states
        }
        dtp[s] = w;
    }
    __syncthreads();

    // ---- phase B: scores -> sc_b (bf16); A2 rows ----
    {
        int l = t >> 2;
        int sbase = (t & 3) * 16;
        unsigned int pk[8];
        #pragma unroll
        for (int jj = 0; jj < 16; jj += 2) {
            float v0 = 0.f, v1 = 0.f;
            int s0 = sbase + jj, s1 = s0 + 1;
            if (s0 <= l) {
                float dot = 0.f;
                #pragma unroll
                for (int n = 0; n < 16; ++n) dot = fmaf(Cc[l][n], Bc[s0][n], dot);
                v0 = dot * __expf(a * (float)(l - s0));
                if (s0 == l) v0 += Dsk;
            }
            if (s1 <= l) {
                float dot = 0.f;
                #pragma unroll
                for (int n = 0; n < 16; ++n) dot = fmaf(Cc[l][n], Bc[s1][n], dot);
                v1 = dot * __expf(a * (float)(l - s1));
                if (s1 == l) v1 += Dsk;
            }
            pk[jj >> 1] = pack2(v0, v1);
        }
        uint4 u0 = {pk[0], pk[1], pk[2], pk[3]};
        uint4 u1 = {pk[4], pk[5], pk[6], pk[7]};
        *(uint4*)&sc_b[l][sbase]     = u0;
        *(uint4*)&sc_b[l][sbase + 8] = u1;
    }
    if (t < 64) {   // A2[t][n] = bf16(exp(a(t+1)) * Cc[t][n]); n>=16 zero
        float e = __expf(a * (float)(t + 1));
        unsigned int pk[8];
        #pragma unroll
        for (int n = 0; n < 16; n += 2) pk[n >> 1] = pack2(e * Cc[t][n], e * Cc[t][n + 1]);
        uint4 u0 = {pk[0], pk[1], pk[2], pk[3]};
        uint4 u1 = {pk[4], pk[5], pk[6], pk[7]};
        uint4 zz = make_uint4(0, 0, 0, 0);
        *(uint4*)&A2[t][0]  = u0;
        *(uint4*)&A2[t][8]  = u1;
        *(uint4*)&A2[t][16] = zz;
        *(uint4*)&A2[t][24] = zz;
    }

    // ---- phase C: rolling-conv x (cur -> xT, prev -> Sp -> SpT) ----
    {
        const int p = t;
        const int xch = h * HEADDIM + p;          // x channel 0..2047
        const float4 w = *(const float4*)&conv_w[(size_t)xch * 4];
        const float cb = conv_b[xch];
        const int colp = 2048 + xch;              // proj column
        {   // current chunk
            const bf16_t* pr = &proj[(size_t)row0 * LDP + colp];
            int l0 = c * CHUNKSZ;
            float xm3 = (l0 >= 3) ? bf2f(pr[-3 * LDP]) : 0.f;
            float xm2 = (l0 >= 2) ? bf2f(pr[-2 * LDP]) : 0.f;
            float xm1 = (l0 >= 1) ? bf2f(pr[-LDP])     : 0.f;
            #pragma unroll
            for (int s0 = 0; s0 < 64; s0 += 8) {
                float xd[8];
                #pragma unroll
                for (int q = 0; q < 8; ++q) {
                    float xc = bf2f(pr[(size_t)(s0 + q) * LDP]);
                    float av = cb;
                    av = fmaf(w.x, xm3, av);
                    av = fmaf(w.y, xm2, av);
                    av = fmaf(w.z, xm1, av);
                    av = fmaf(w.w, xc, av);
                    xd[q] = siluf_(av) * dtc[s0 + q];
                    xm3 = xm2; xm2 = xm1; xm1 = xc;
                }
                uint4 u;
                u.x = pack2(xd[0], xd[1]); u.y = pack2(xd[2], xd[3]);
                u.z = pack2(xd[4], xd[5]); u.w = pack2(xd[6], xd[7]);
                *(uint4*)&xT[p][s0] = u;
            }
        }
        float Sp[16];
        #pragma unroll
        for (int n = 0; n < 16; ++n) Sp[n] = 0.f;
        if (c > 0) {   // previous chunk -> incoming state
            const bf16_t* pr = &proj[(size_t)(row0 - CHUNKSZ) * LDP + colp];
            int l0 = (c - 1) * CHUNKSZ;
            float xm3 = (l0 >= 3) ? bf2f(pr[-3 * LDP]) : 0.f;
            float xm2 = (l0 >= 2) ? bf2f(pr[-2 * LDP]) : 0.f;
            float xm1 = (l0 >= 1) ? bf2f(pr[-LDP])     : 0.f;
            for (int s = 0; s < 64; ++s) {
                float xc = bf2f(pr[(size_t)s * LDP]);
                float av = cb;
                av = fmaf(w.x, xm3, av);
                av = fmaf(w.y, xm2, av);
                av = fmaf(w.z, xm1, av);
                av = fmaf(w.w, xc, av);
                float v = siluf_(av) * dtp[s];
                #pragma unroll
                for (int n = 0; n < 16; ++n) Sp[n] = fmaf(Bp[s][n], v, Sp[n]);
                xm3 = xm2; xm2 = xm1; xm1 = xc;
            }
        }
        unsigned int pk[8];
        #pragma unroll
        for (int n = 0; n < 16; n += 2) pk[n >> 1] = pack2(Sp[n], Sp[n + 1]);
        uint4 u0 = {pk[0], pk[1], pk[2], pk[3]};
        uint4 u1 = {pk[4], pk[5], pk[6], pk[7]};
        uint4 zz = make_uint4(0, 0, 0, 0);
        *(uint4*)&SpT[p][0]  = u0;
        *(uint4*)&SpT[p][8]  = u1;
        *(uint4*)&SpT[p][16] = zz;
        *(uint4*)&SpT[p][24] = zz;
    }
    __syncthreads();

    // ---- phase D: MFMA + staged coalesced epilogue ----
    {
        const int wave = t >> 6, lane = t & 63;
        const int quad = lane >> 4, fr = lane & 15;
        f32x4 acc[4][4];
        #pragma unroll
        for (int i = 0; i < 4; ++i)
            #pragma unroll
            for (int j = 0; j < 4; ++j) {
                f32x4 z = {0.f, 0.f, 0.f, 0.f};
                acc[i][j] = z;
            }
        #pragma unroll
        for (int kk = 0; kk < 2; ++kk) {
            bfrag af[4], bfr[4];
            #pragma unroll
            for (int i = 0; i < 4; ++i)
                af[i] = *(const bfrag*)&sc_b[16 * i + fr][32 * kk + quad * 8];
            #pragma unroll
            for (int j = 0; j < 4; ++j)
                bfr[j] = *(const bfrag*)&xT[64 * wave + 16 * j + fr][32 * kk + quad * 8];
            #pragma unroll
            for (int i = 0; i < 4; ++i)
                #pragma unroll
                for (int j = 0; j < 4; ++j)
                    acc[i][j] = __builtin_amdgcn_mfma_f32_16x16x32_bf16(
                                    af[i], bfr[j], acc[i][j], 0, 0, 0);
        }
        {   // off-chunk term: K=32 over n (16 real + 16 zero)
            bfrag af[4], bfr[4];
            #pragma unroll
            for (int i = 0; i < 4; ++i)
                af[i] = *(const bfrag*)&A2[16 * i + fr][quad * 8];
            #pragma unroll
            for (int j = 0; j < 4; ++j)
                bfr[j] = *(const bfrag*)&SpT[64 * wave + 16 * j + fr][quad * 8];
            #pragma unroll
            for (int i = 0; i < 4; ++i)
                #pragma unroll
                for (int j = 0; j < 4; ++j)
                    acc[i][j] = __builtin_amdgcn_mfma_f32_16x16x32_bf16(
                                    af[i], bfr[j], acc[i][j], 0, 0, 0);
        }
        __syncthreads();                    // all MFMA reads of xT done
        bf16_t* buf = &xT[0][0];            // reuse as Y[64][264]
        #pragma unroll
        for (int i = 0; i < 4; ++i)
            #pragma unroll
            for (int j = 0; j < 4; ++j) {
                int pc = 64 * wave + 16 * j + fr;
                #pragma unroll
                for (int r = 0; r < 4; ++r) {
                    int l = 16 * i + quad * 4 + r;
                    buf[l * 264 + pc] = f2bf(acc[i][j][r]);
                }
            }
        __syncthreads();
        bf16_t* ybase = &ybuf[(size_t)row0 * DINNER + h * HEADDIM];
        #pragma unroll
        for (int k = 0; k < 8; ++k) {
            int id = k * 256 + t;
            int l = id >> 5, ch = id & 31;
            uint4 v = *(const uint4*)&buf[l * 264 + ch * 8];
            *(uint4*)&ybase[(size_t)l * DINNER + ch * 8] = v;
        }
    }
}

// ---------------------------------------------------------------------------
// g = Y*silu(z) in place on ybuf; rowscale[i] = rms scale.
// ---------------------------------------------------------------------------
__global__ __launch_bounds__(256)
void gate_kernel(const bf16_t* __restrict__ proj, bf16_t* __restrict__ ybuf,
                 float* __restrict__ rowscale)
{
    __shared__ float red[4];
    int i = blockIdx.x;
    int t = threadIdx.x;
    const bf16_t* zrow = &proj[(size_t)i * LDP];
    bf16_t* yrow = &ybuf[(size_t)i * DINNER];
    uint4 yv = *(const uint4*)&yrow[t * 8];
    uint4 zv = *(const uint4*)&zrow[t * 8];
    float ya[8] = {bflo(yv.x), bfhi(yv.x), bflo(yv.y), bfhi(yv.y),
                   bflo(yv.z), bfhi(yv.z), bflo(yv.w), bfhi(yv.w)};
    float za[8] = {bflo(zv.x), bfhi(zv.x), bflo(zv.y), bfhi(zv.y),
                   bflo(zv.z), bfhi(zv.z), bflo(zv.w), bfhi(zv.w)};
    float g[8];
    float ss = 0.f;
    #pragma unroll
    for (int j = 0; j < 8; ++j) {
        float gv = ya[j] * siluf_(za[j]);
        g[j] = gv;
        ss = fmaf(gv, gv, ss);
    }
    #pragma unroll
    for (int off = 32; off >= 1; off >>= 1) ss += __shfl_down(ss, off);
    if ((t & 63) == 0) red[t >> 6] = ss;
    __syncthreads();
    if (t == 0) {
        float tot = red[0] + red[1] + red[2] + red[3];
        rowscale[i] = rsqrtf(tot / (float)DINNER + 1e-5f);
    }
    uint4 o;
    o.x = pack2(g[0], g[1]); o.y = pack2(g[2], g[3]);
    o.z = pack2(g[4], g[5]); o.w = pack2(g[6], g[7]);
    *(uint4*)&yrow[t * 8] = o;
}

// ---------------------------------------------------------------------------
extern "C" void kernel_launch(void* const* d_in, const int* in_sizes, int n_in,
                              void* d_out, int out_size, void* d_ws, size_t ws_size,
                              hipStream_t stream)
{
    const float* input   = (const float*)d_in[0];
    const float* W_in    = (const float*)d_in[1];
    const float* conv_w  = (const float*)d_in[2];
    const float* conv_b  = (const float*)d_in[3];
    const float* dt_bias = (const float*)d_in[4];
    const float* log_A   = (const float*)d_in[5];
    const float* D_skip  = (const float*)d_in[6];
    const float* norm_w  = (const float*)d_in[7];
    const float* W_out   = (const float*)d_in[8];
    float* out = (float*)d_out;

    // workspace: proj(138.4MB, stride 4224) | region1 (68.2MB) | Wb2 | rowscale
    // region1: phase-1 = Ab(33.5)+Wb1(8.9, 4352 rows); phase-2 = ybuf (67.1MB)
    bf16_t* proj  = (bf16_t*)d_ws;
    bf16_t* region1 = proj + (size_t)ROWS * LDP;
    bf16_t* Wb2   = region1 + (size_t)ROWS * CONVDIM;
    float*  rowscale = (float*)(Wb2 + (size_t)DMODEL * DINNER);
    bf16_t* Ab    = region1;                     // alias (phase 1 only)
    bf16_t* Wb1   = Ab + (size_t)ROWS * DMODEL;  // alias (phase 1 only)
    bf16_t* ybuf  = region1;                     // alias (phase 2)

    size_t need = (size_t)ROWS * LDP * 2 + (size_t)ROWS * CONVDIM * 2
                + (size_t)DMODEL * DINNER * 2 + (size_t)ROWS * 4;
    if (ws_size < need) {
        hipMemsetAsync(d_out, 0, (size_t)out_size * sizeof(float), stream);
        return;
    }

    // 0) bf16 conversions (+ norm_w folded into Wb2)
    cvt_f32_bf16<<<(ROWS * DMODEL / 8 + 255) / 256, 256, 0, stream>>>(
        input, Ab, ROWS * DMODEL / 8);
    cvt_pad_w1<<<(NPADW * DMODEL / 4 + 255) / 256, 256, 0, stream>>>(W_in, Wb1);
    cvt_w2<<<(DMODEL * DINNER / 4 + 255) / 256, 256, 0, stream>>>(W_out, norm_w, Wb2);

    // 1) proj = input @ W_in^T  (256^2 fine-interleaved MFMA; M=16384, K=1024)
    dim3 g1(NPADW / 256, ROWS / 256);            // 17 x 64 (nwg%8==0)
    gemm_g1<<<g1, 512, 0, stream>>>(Ab, Wb1, proj, nullptr,
                                    LDP, DMODEL, DMODEL, DMODEL, LDP);
    // 2) fused conv+SSD -> ybuf   (Ab/Wb1 dead from here)
    dim3 gs(NCHUNK, NHEADS, BATCH);
    ssd_fused<<<gs, 256, 0, stream>>>(proj, conv_w, conv_b, dt_bias,
                                      log_A, D_skip, ybuf);
    // 3) gate: g = Y*silu(z) in place on ybuf + per-row RMS scale
    gate_kernel<<<ROWS, 256, 0, stream>>>(proj, ybuf, rowscale);
    // 4) out = g @ (W_out*norm_w)^T * rowscale  (256^2 MFMA; N=1024, K=2048)
    dim3 g2(DMODEL / 256, ROWS / 256);           // 4 x 64 (nwg%8==0)
    gemm_g2<<<g2, 512, 0, stream>>>(ybuf, Wb2, out, rowscale,
                                    DMODEL, DINNER, DINNER, DINNER, DMODEL);
}

// Round 5
// 541.373 us; speedup vs baseline: 1.0028x; 1.0028x over previous
//
#include <hip/hip_runtime.h>
#include <hip/hip_bf16.h>
#include <math.h>

#define BATCH   4
#define SEQLEN  4096
#define DMODEL  1024
#define DSTATE  16
#define DCONV   4
#define NHEADS  8
#define CHUNKSZ 64
#define DINNER  2048
#define HEADDIM 256          // DINNER / NHEADS
#define CONVDIM 2080         // DINNER + 2*DSTATE
#define DPROJ   4136         // 2*DINNER + 2*DSTATE + NHEADS
#define NPADW   4352         // W_in rows padded to multiple of 256 (17 N-tiles)
#define LDP     4224         // proj row stride (8448 B = 64B-aligned rows)
#define ROWS    (BATCH*SEQLEN)   // 16384
#define NCHUNK  (SEQLEN/CHUNKSZ) // 64

typedef unsigned short bf16_t;
typedef __attribute__((ext_vector_type(8))) short bfrag;    // 8 bf16 = 4 VGPRs
typedef __attribute__((ext_vector_type(4))) float f32x4;
typedef __attribute__((ext_vector_type(16))) float f32x16;  // 32x32 accumulator

__device__ __forceinline__ float sigmoidf_(float v) { return 1.0f / (1.0f + __expf(-v)); }
__device__ __forceinline__ float siluf_(float v)    { return v * sigmoidf_(v); }
__device__ __forceinline__ float softplusf_(float v) {
    return fmaxf(v, 0.f) + log1pf(__expf(-fabsf(v)));
}

__device__ __forceinline__ float bf2f(bf16_t u) {
    union { unsigned int i; float f; } v; v.i = ((unsigned int)u) << 16; return v.f;
}
__device__ __forceinline__ float bflo(unsigned int u) {
    union { unsigned int i; float f; } v; v.i = u << 16; return v.f;
}
__device__ __forceinline__ float bfhi(unsigned int u) {
    union { unsigned int i; float f; } v; v.i = u & 0xffff0000u; return v.f;
}
__device__ __forceinline__ bf16_t f2bf(float f) {   // round-to-nearest-even
    unsigned int x = __float_as_uint(f);
    unsigned int r = (x + 0x7fffu + ((x >> 16) & 1u)) >> 16;
    return (bf16_t)r;
}
__device__ __forceinline__ unsigned int pack2(float a, float b) {
    return (unsigned int)f2bf(a) | ((unsigned int)f2bf(b) << 16);
}

__device__ __forceinline__ void async_copy16(const bf16_t* g, bf16_t* l) {
    __builtin_amdgcn_global_load_lds(
        (const __attribute__((address_space(1))) void*)g,
        (__attribute__((address_space(3))) void*)l, 16, 0, 0);
}

#define WAITV(N)  asm volatile("s_waitcnt vmcnt(" #N ")" ::: "memory")
__device__ __forceinline__ void barrier_() {
    __builtin_amdgcn_s_barrier();
    asm volatile("" ::: "memory");
}

// ---------------------------------------------------------------------------
// conversion kernels
// ---------------------------------------------------------------------------
__global__ __launch_bounds__(256)
void cvt_f32_bf16(const float* __restrict__ src, bf16_t* __restrict__ dst, int n8)
{
    int i = blockIdx.x * 256 + threadIdx.x;
    if (i >= n8) return;
    float4 a = *(const float4*)&src[(size_t)i * 8];
    float4 b = *(const float4*)&src[(size_t)i * 8 + 4];
    uint4 o;
    o.x = pack2(a.x, a.y); o.y = pack2(a.z, a.w);
    o.z = pack2(b.x, b.y); o.w = pack2(b.z, b.w);
    *(uint4*)&dst[(size_t)i * 8] = o;
}

// W_in (4136x1024) -> bf16 padded to 4352 rows (zeros)
__global__ __launch_bounds__(256)
void cvt_pad_w1(const float* __restrict__ src, bf16_t* __restrict__ dst)
{
    int i = blockIdx.x * 256 + threadIdx.x;
    if (i >= NPADW * DMODEL / 4) return;
    size_t e = (size_t)i * 4;
    int row = (int)(e >> 10);
    ushort4 o = make_ushort4(0, 0, 0, 0);
    if (row < DPROJ) {
        float4 v = *(const float4*)&src[e];
        o.x = f2bf(v.x); o.y = f2bf(v.y); o.z = f2bf(v.z); o.w = f2bf(v.w);
    }
    *(ushort4*)&dst[e] = o;
}

// Wb2[n][k] = bf16(W_out[n][k] * norm_w[k])  — norm folded into the weight
__global__ __launch_bounds__(256)
void cvt_w2(const float* __restrict__ W, const float* __restrict__ norm_w,
            bf16_t* __restrict__ dst)
{
    int i = blockIdx.x * 256 + threadIdx.x;
    if (i >= DMODEL * DINNER / 4) return;
    size_t e = (size_t)i * 4;
    int k = (int)(e & (DINNER - 1));
    float4 v = *(const float4*)&W[e];
    float4 w = *(const float4*)&norm_w[k];
    ushort4 o;
    o.x = f2bf(v.x * w.x); o.y = f2bf(v.y * w.y);
    o.z = f2bf(v.z * w.z); o.w = f2bf(v.w * w.w);
    *(ushort4*)&dst[e] = o;
}

// ---------------------------------------------------------------------------
// 256x256 MFMA GEMM, barrier-light schedule + 32x32x16 MFMA.
// 512 threads = 8 waves (2Mx4N), per-wave 128x64 output = 4x2 blocks of 32x32.
// Per K-tile (BK=64): ONE vmcnt(0)+barrier at tile top, then two free-running
// phases: {ld frags ks01 | stage t+1 A-halves -> buf^1 | 16 MFMA} then
// {ld frags ks23 | stage t+1 B-halves -> buf^1 | 16 MFMA}. Staging only ever
// targets the INACTIVE buffer, so no in-buffer hazards; the tile-top barrier
// (arrival implies all waves' ds_reads of buf^1 completed, since each read
// feeds an MFMA whose compiler-inserted lgkm wait precedes barrier arrival)
// makes buf^1 restaging safe. Waves free-run between barriers -> ds_read
// latency overlaps the SIMD-mate's MFMA. vmcnt(0) retires loads issued a
// full tile (~2000+cy) earlier: effectively free.
// A/B frag layout (32x32x16): row/col = lane&31, k = (lane>>5)*8 + elem.
// C/D layout: col = lane&31, row = (reg&3) + 8*(reg>>2) + 4*(lane>>5).
// ---------------------------------------------------------------------------
__device__ __forceinline__
void ld_a32(bfrag (&a)[4][2], const bf16_t* base, int wm, int lane, int k0)
{
    const int r5 = lane & 31, hi = lane >> 5;
    #pragma unroll
    for (int ks = 0; ks < 2; ++ks)
        #pragma unroll
        for (int rb = 0; rb < 4; ++rb) {
            int row = wm + rb * 32 + r5;
            int chunk = (2 * (k0 + ks) + hi) ^ (row & 7);
            a[rb][ks] = *(const bfrag*)&base[row * 64 + chunk * 8];
        }
}
__device__ __forceinline__
void ld_b32(bfrag (&b)[2][2], const bf16_t* base, int wn, int lane, int k0)
{
    const int r5 = lane & 31, hi = lane >> 5;
    #pragma unroll
    for (int ks = 0; ks < 2; ++ks)
        #pragma unroll
        for (int cb = 0; cb < 2; ++cb) {
            int row = wn + cb * 32 + r5;
            int chunk = (2 * (k0 + ks) + hi) ^ (row & 7);
            b[cb][ks] = *(const bfrag*)&base[row * 64 + chunk * 8];
        }
}
__device__ __forceinline__
void mm16(f32x16 (&acc)[4][2], const bfrag (&a)[4][2], const bfrag (&b)[2][2])
{
    __builtin_amdgcn_s_setprio(1);
    #pragma unroll
    for (int ks = 0; ks < 2; ++ks)
        #pragma unroll
        for (int rb = 0; rb < 4; ++rb)
            #pragma unroll
            for (int cb = 0; cb < 2; ++cb)
                acc[rb][cb] = __builtin_amdgcn_mfma_f32_32x32x16_bf16(
                    a[rb][ks], b[cb][ks], acc[rb][cb], 0, 0, 0);
    __builtin_amdgcn_s_setprio(0);
}

template<bool OUT_BF16>
__device__ __forceinline__
void gemm256_body(const bf16_t* __restrict__ A, const bf16_t* __restrict__ W,
                  void* __restrict__ Cv, const float* __restrict__ rowSum,
                  int Nstore, int K, int lda, int ldw, int ldc)
{
    __shared__ __align__(16) bf16_t smem[65536];   // 128 KiB
    bf16_t* As = smem;            // [2][256][64]
    bf16_t* Ws = smem + 32768;    // [2][256][64]

    const int tid  = threadIdx.x;
    const int wave = tid >> 6, lane = tid & 63;
    const int ln3  = lane >> 3;
    const int cswz = ((lane & 7) ^ ln3) * 8;       // pre-swizzled source column

    const int gx   = gridDim.x;
    const int nwg  = gx * gridDim.y;
    const int flat = blockIdx.y * gx + blockIdx.x;
    const int q8   = nwg >> 3;                     // nwg % 8 == 0 at both call sites
    const int swz  = (flat & 7) * q8 + (flat >> 3);
    const int col0 = (swz % gx) * 256;
    const int row0 = (swz / gx) * 256;

    const int wm = (wave >> 2) * 128, wn = (wave & 3) * 64;

    // staging source pointers: 2 halves x 2 calls each for A and W.
    const bf16_t* gA[2][2];
    const bf16_t* gW[2][2];
    #pragma unroll
    for (int h = 0; h < 2; ++h)
        #pragma unroll
        for (int q = 0; q < 2; ++q) {
            int rA = 128*q + 8*wave + 64*h;
            int rB = 128*q + 64*(wave >> 2) + 8*(wave & 3) + 32*h;
            gA[h][q] = A + (size_t)(row0 + rA + ln3) * lda + cswz;
            gW[h][q] = W + (size_t)(col0 + rB + ln3) * ldw + cswz;
        }

#define STG_A(H, Q, NB, K0S)                                                     \
    async_copy16(gA[H][Q] + (K0S),                                               \
                 &As[(NB)*16384 + (128*(Q) + 8*wave + 64*(H))*64])
#define STG_B(H, Q, NB, K0S)                                                     \
    async_copy16(gW[H][Q] + (K0S),                                               \
                 &Ws[(NB)*16384 + (128*(Q) + 64*(wave>>2) + 8*(wave&3) + 32*(H))*64])

    f32x16 acc[4][2];
    #pragma unroll
    for (int i = 0; i < 4; ++i)
        #pragma unroll
        for (int j = 0; j < 2; ++j)
            #pragma unroll
            for (int r = 0; r < 16; ++r)
                acc[i][j][r] = 0.f;
    bfrag afr[4][2], bfr[2][2];

    // prologue: stage tile 0 into buf 0 (8 calls)
    STG_A(0,0,0,0); STG_A(0,1,0,0); STG_A(1,0,0,0); STG_A(1,1,0,0);
    STG_B(0,0,0,0); STG_B(0,1,0,0); STG_B(1,0,0,0); STG_B(1,1,0,0);

    const int nt = K >> 6;
    for (int t = 0; t < nt; ++t) {
        const int cur = (t & 1) * 16384;
        const int nb  = (t + 1) & 1;
        const int ko  = (t + 1) * 64;
        const bool stg = (t + 1 < nt);
        WAITV(0);        // retire tile t's 8 calls (issued >= 1 tile ago)
        barrier_();      // all waves done reading buf^1 (tile t-1) -> restage ok
        // phase A: ks 0,1
        ld_a32(afr, As + cur, wm, lane, 0);
        ld_b32(bfr, Ws + cur, wn, lane, 0);
        if (stg) { STG_A(0,0,nb,ko); STG_A(0,1,nb,ko);
                   STG_A(1,0,nb,ko); STG_A(1,1,nb,ko); }
        mm16(acc, afr, bfr);
        // phase B: ks 2,3 (no barrier: same buf, disjoint reg refill after use)
        ld_a32(afr, As + cur, wm, lane, 2);
        ld_b32(bfr, Ws + cur, wn, lane, 2);
        if (stg) { STG_B(0,0,nb,ko); STG_B(0,1,nb,ko);
                   STG_B(1,0,nb,ko); STG_B(1,1,nb,ko); }
        mm16(acc, afr, bfr);
    }

#undef STG_A
#undef STG_B

    const int c32 = lane & 31, hi4 = (lane >> 5) * 4;
    if (OUT_BF16) {
        // LDS-staged coalesced epilogue: two 128-row passes through smem[128][264]
        __syncthreads();
        bf16_t* C = (bf16_t*)Cv;
        #pragma unroll
        for (int pass = 0; pass < 2; ++pass) {
            if ((wave >> 2) == pass) {
                #pragma unroll
                for (int rb = 0; rb < 4; ++rb)
                    #pragma unroll
                    for (int cb = 0; cb < 2; ++cb) {
                        int col = wn + cb * 32 + c32;
                        #pragma unroll
                        for (int reg = 0; reg < 16; ++reg) {
                            int rl = rb * 32 + (reg & 3) + 8 * (reg >> 2) + hi4;
                            smem[rl * 264 + col] = f2bf(acc[rb][cb][reg]);
                        }
                    }
            }
            __syncthreads();
            #pragma unroll
            for (int k = 0; k < 8; ++k) {
                int id = k * 512 + tid;
                int rl = id >> 5, ch = id & 31;
                if (col0 + ch * 8 < Nstore) {
                    uint4 v = *(const uint4*)&smem[rl * 264 + ch * 8];
                    *(uint4*)&C[(size_t)(row0 + pass * 128 + rl) * ldc
                                + col0 + ch * 8] = v;
                }
            }
            if (pass == 0) __syncthreads();
        }
    } else {
        // f32 direct stores; RMS scale computed from raw row sum-of-squares
        float* C = (float*)Cv;
        #pragma unroll
        for (int rb = 0; rb < 4; ++rb) {
            float rs[16];
            #pragma unroll
            for (int reg = 0; reg < 16; ++reg) {
                size_t m = (size_t)row0 + wm + rb * 32
                         + (reg & 3) + 8 * (reg >> 2) + hi4;
                rs[reg] = rowSum ? rsqrtf(rowSum[m] * (1.f / DINNER) + 1e-5f) : 1.f;
            }
            #pragma unroll
            for (int cb = 0; cb < 2; ++cb) {
                int n = col0 + wn + cb * 32 + c32;
                if (n < Nstore) {
                    #pragma unroll
                    for (int reg = 0; reg < 16; ++reg) {
                        size_t m = (size_t)row0 + wm + rb * 32
                                 + (reg & 3) + 8 * (reg >> 2) + hi4;
                        C[m * ldc + n] = acc[rb][cb][reg] * rs[reg];
                    }
                }
            }
        }
    }
}

// distinct names for profiler attribution
__global__ __launch_bounds__(512, 2)
void gemm_g1(const bf16_t* __restrict__ A, const bf16_t* __restrict__ W,
             void* __restrict__ Cv, const float* __restrict__ rowSum,
             int Nstore, int K, int lda, int ldw, int ldc)
{ gemm256_body<true>(A, W, Cv, rowSum, Nstore, K, lda, ldw, ldc); }

__global__ __launch_bounds__(512, 2)
void gemm_g2(const bf16_t* __restrict__ A, const bf16_t* __restrict__ W,
             void* __restrict__ Cv, const float* __restrict__ rowSum,
             int Nstore, int K, int lda, int ldw, int ldc)
{ gemm256_body<false>(A, W, Cv, rowSum, Nstore, K, lda, ldw, ldc); }

// ---------------------------------------------------------------------------
// Fused conv+SSD. One block per (chunk, head, batch), 256 threads.
// Epilogue now also applies the gate g = Y*silu(z) (z from proj cols 0..2047)
// and accumulates per-row sum(g^2) into rowsum via one atomicAdd per 32-lane
// group -> gate_kernel eliminated (saves a full ybuf round-trip pass).
// ---------------------------------------------------------------------------
__global__ __launch_bounds__(256)
void ssd_fused(const bf16_t* __restrict__ proj, const float* __restrict__ conv_w,
               const float* __restrict__ conv_b, const float* __restrict__ dt_bias,
               const float* __restrict__ log_A, const float* __restrict__ D_skip,
               bf16_t* __restrict__ ybuf, float* __restrict__ rowsum)
{
    __shared__ float Bc[64][16];
    __shared__ float Cc[64][16];
    __shared__ float Bp[64][16];
    __shared__ float dtc[64];
    __shared__ float dtp[64];
    __shared__ __align__(16) bf16_t sc_b[64][72];   // scores
    __shared__ __align__(16) bf16_t xT[256][72];    // x*dt; reused as Y[64][264]
    __shared__ __align__(16) bf16_t SpT[256][32];   // SpT[p][n], n>=16 zero
    __shared__ __align__(16) bf16_t A2[64][32];     // e(l)*C[l][n], n>=16 zero

    const int c = blockIdx.x, h = blockIdx.y, b = blockIdx.z;
    const int t = threadIdx.x;
    const int row0 = b * SEQLEN + c * CHUNKSZ;
    const float a   = -__expf(log_A[h]);
    const float Dsk = D_skip[h];
    const float bias = dt_bias[h];

    // ---- phase A1: cur-chunk B/C conv+silu (all 256 threads) ----
    {
        int s = t >> 2, ch8 = (t & 3) * 8;      // 8 channels of [0,32)
        int l = c * CHUNKSZ + s;
        const bf16_t* base = &proj[(size_t)(row0 + s) * LDP + 4096 + ch8];
        uint4 zz = make_uint4(0, 0, 0, 0);
        uint4 u3 = *(const uint4*)&base[0];
        uint4 u2 = (l >= 1) ? *(const uint4*)&base[-LDP]     : zz;
        uint4 u1 = (l >= 2) ? *(const uint4*)&base[-2 * LDP] : zz;
        uint4 u0 = (l >= 3) ? *(const uint4*)&base[-3 * LDP] : zz;
        float t3[8] = {bflo(u3.x), bfhi(u3.x), bflo(u3.y), bfhi(u3.y),
                       bflo(u3.z), bfhi(u3.z), bflo(u3.w), bfhi(u3.w)};
        float t2[8] = {bflo(u2.x), bfhi(u2.x), bflo(u2.y), bfhi(u2.y),
                       bflo(u2.z), bfhi(u2.z), bflo(u2.w), bfhi(u2.w)};
        float t1[8] = {bflo(u1.x), bfhi(u1.x), bflo(u1.y), bfhi(u1.y),
                       bflo(u1.z), bfhi(u1.z), bflo(u1.w), bfhi(u1.w)};
        float t0[8] = {bflo(u0.x), bfhi(u0.x), bflo(u0.y), bfhi(u0.y),
                       bflo(u0.z), bfhi(u0.z), bflo(u0.w), bfhi(u0.w)};
        #pragma unroll
        for (int j = 0; j < 8; ++j) {
            int ch = ch8 + j;
            float4 w = *(const float4*)&conv_w[(2048 + ch) * 4];
            float av = conv_b[2048 + ch];
            av = fmaf(w.x, t0[j], av);
            av = fmaf(w.y, t1[j], av);
            av = fmaf(w.z, t2[j], av);
            av = fmaf(w.w, t3[j], av);
            float v = siluf_(av);
            if (ch < 16) Bc[s][ch] = v; else Cc[s][ch - 16] = v;
        }
    }
    // ---- phase A2: prev-chunk B conv (t<128) | dt cur/prev (t>=128) ----
    if (t < 128) {
        int s = t >> 1, ch8 = (t & 1) * 8;      // 8 channels of [0,16)
        float vout[8];
        #pragma unroll
        for (int j = 0; j < 8; ++j) vout[j] = 0.f;
        if (c > 0) {
            int l = (c - 1) * CHUNKSZ + s;
            const bf16_t* base = &proj[(size_t)(row0 - CHUNKSZ + s) * LDP + 4096 + ch8];
            uint4 zz = make_uint4(0, 0, 0, 0);
            uint4 u3 = *(const uint4*)&base[0];
            uint4 u2 = (l >= 1) ? *(const uint4*)&base[-LDP]     : zz;
            uint4 u1 = (l >= 2) ? *(const uint4*)&base[-2 * LDP] : zz;
            uint4 u0 = (l >= 3) ? *(const uint4*)&base[-3 * LDP] : zz;
            float t3[8] = {bflo(u3.x), bfhi(u3.x), bflo(u3.y), bfhi(u3.y),
                           bflo(u3.z), bfhi(u3.z), bflo(u3.w), bfhi(u3.w)};
            float t2[8] = {bflo(u2.x), bfhi(u2.x), bflo(u2.y), bfhi(u2.y),
                           bflo(u2.z), bfhi(u2.z), bflo(u2.w), bfhi(u2.w)};
            float t1[8] = {bflo(u1.x), bfhi(u1.x), bflo(u1.y), bfhi(u1.y),
                           bflo(u1.z), bfhi(u1.z), bflo(u1.w), bfhi(u1.w)};
            float t0[8] = {bflo(u0.x), bfhi(u0.x), bflo(u0.y), bfhi(u0.y),
                           bflo(u0.z), bfhi(u0.z), bflo(u0.w), bfhi(u0.w)};
            #pragma unroll
            for (int j = 0; j < 8; ++j) {
                int ch = ch8 + j;
                float4 w = *(const float4*)&conv_w[(2048 + ch) * 4];
                float av = conv_b[2048 + ch];
                av = fmaf(w.x, t0[j], av);
                av = fmaf(w.y, t1[j], av);
                av = fmaf(w.z, t2[j], av);
                av = fmaf(w.w, t3[j], av);
                vout[j] = siluf_(av);
            }
        }
        #pragma unroll
        for (int j = 0; j < 8; ++j) Bp[s][ch8 + j] = vout[j];
    } else if (t < 192) {
        int s = t - 128;
        float v = bf2f(proj[(size_t)(row0 + s) * LDP + 4128 + h]) + bias;
        dtc[s] = softplusf_(v);
    } else {
        int s = t - 192;
        float w = 0.f;
        if (c > 0) {
            float v = bf2f(proj[(size_t)(row0 - CHUNKSZ + s) * LDP + 4128 + h]) + bias;
            w = softplusf_(v) * __expf(a * (float)(63 - s));   // fold decay_states
        }
        dtp[s] = w;
    }
    __syncthreads();

    // ---- phase B: scores -> sc_b (bf16); A2 rows ----
    {
        int l = t >> 2;
        int sbase = (t & 3) * 16;
        unsigned int pk[8];
        #pragma unroll
        for (int jj = 0; jj < 16; jj += 2) {
            float v0 = 0.f, v1 = 0.f;
            int s0 = sbase + jj, s1 = s0 + 1;
            if (s0 <= l) {
                float dot = 0.f;
                #pragma unroll
                for (int n = 0; n < 16; ++n) dot = fmaf(Cc[l][n], Bc[s0][n], dot);
                v0 = dot * __expf(a * (float)(l - s0));
                if (s0 == l) v0 += Dsk;
            }
            if (s1 <= l) {
                float dot = 0.f;
                #pragma unroll
                for (int n = 0; n < 16; ++n) dot = fmaf(Cc[l][n], Bc[s1][n], dot);
                v1 = dot * __expf(a * (float)(l - s1));
                if (s1 == l) v1 += Dsk;
            }
            pk[jj >> 1] = pack2(v0, v1);
        }
        uint4 u0 = {pk[0], pk[1], pk[2], pk[3]};
        uint4 u1 = {pk[4], pk[5], pk[6], pk[7]};
        *(uint4*)&sc_b[l][sbase]     = u0;
        *(uint4*)&sc_b[l][sbase + 8] = u1;
    }
    if (t < 64) {   // A2[t][n] = bf16(exp(a(t+1)) * Cc[t][n]); n>=16 zero
        float e = __expf(a * (float)(t + 1));
        unsigned int pk[8];
        #pragma unroll
        for (int n = 0; n < 16; n += 2) pk[n >> 1] = pack2(e * Cc[t][n], e * Cc[t][n + 1]);
        uint4 u0 = {pk[0], pk[1], pk[2], pk[3]};
        uint4 u1 = {pk[4], pk[5], pk[6], pk[7]};
        uint4 zz = make_uint4(0, 0, 0, 0);
        *(uint4*)&A2[t][0]  = u0;
        *(uint4*)&A2[t][8]  = u1;
        *(uint4*)&A2[t][16] = zz;
        *(uint4*)&A2[t][24] = zz;
    }

    // ---- phase C: rolling-conv x (cur -> xT, prev -> Sp -> SpT) ----
    {
        const int p = t;
        const int xch = h * HEADDIM + p;          // x channel 0..2047
        const float4 w = *(const float4*)&conv_w[(size_t)xch * 4];
        const float cb = conv_b[xch];
        const int colp = 2048 + xch;              // proj column
        {   // current chunk
            const bf16_t* pr = &proj[(size_t)row0 * LDP + colp];
            int l0 = c * CHUNKSZ;
            float xm3 = (l0 >= 3) ? bf2f(pr[-3 * LDP]) : 0.f;
            float xm2 = (l0 >= 2) ? bf2f(pr[-2 * LDP]) : 0.f;
            float xm1 = (l0 >= 1) ? bf2f(pr[-LDP])     : 0.f;
            #pragma unroll
            for (int s0 = 0; s0 < 64; s0 += 8) {
                float xd[8];
                #pragma unroll
                for (int q = 0; q < 8; ++q) {
                    float xc = bf2f(pr[(size_t)(s0 + q) * LDP]);
                    float av = cb;
                    av = fmaf(w.x, xm3, av);
                    av = fmaf(w.y, xm2, av);
                    av = fmaf(w.z, xm1, av);
                    av = fmaf(w.w, xc, av);
                    xd[q] = siluf_(av) * dtc[s0 + q];
                    xm3 = xm2; xm2 = xm1; xm1 = xc;
                }
                uint4 u;
                u.x = pack2(xd[0], xd[1]); u.y = pack2(xd[2], xd[3]);
                u.z = pack2(xd[4], xd[5]); u.w = pack2(xd[6], xd[7]);
                *(uint4*)&xT[p][s0] = u;
            }
        }
        float Sp[16];
        #pragma unroll
        for (int n = 0; n < 16; ++n) Sp[n] = 0.f;
        if (c > 0) {   // previous chunk -> incoming state
            const bf16_t* pr = &proj[(size_t)(row0 - CHUNKSZ) * LDP + colp];
            int l0 = (c - 1) * CHUNKSZ;
            float xm3 = (l0 >= 3) ? bf2f(pr[-3 * LDP]) : 0.f;
            float xm2 = (l0 >= 2) ? bf2f(pr[-2 * LDP]) : 0.f;
            float xm1 = (l0 >= 1) ? bf2f(pr[-LDP])     : 0.f;
            for (int s = 0; s < 64; ++s) {
                float xc = bf2f(pr[(size_t)s * LDP]);
                float av = cb;
                av = fmaf(w.x, xm3, av);
                av = fmaf(w.y, xm2, av);
                av = fmaf(w.z, xm1, av);
                av = fmaf(w.w, xc, av);
                float v = siluf_(av) * dtp[s];
                #pragma unroll
                for (int n = 0; n < 16; ++n) Sp[n] = fmaf(Bp[s][n], v, Sp[n]);
                xm3 = xm2; xm2 = xm1; xm1 = xc;
            }
        }
        unsigned int pk[8];
        #pragma unroll
        for (int n = 0; n < 16; n += 2) pk[n >> 1] = pack2(Sp[n], Sp[n + 1]);
        uint4 u0 = {pk[0], pk[1], pk[2], pk[3]};
        uint4 u1 = {pk[4], pk[5], pk[6], pk[7]};
        uint4 zz = make_uint4(0, 0, 0, 0);
        *(uint4*)&SpT[p][0]  = u0;
        *(uint4*)&SpT[p][8]  = u1;
        *(uint4*)&SpT[p][16] = zz;
        *(uint4*)&SpT[p][24] = zz;
    }
    __syncthreads();

    // ---- phase D: MFMA + gated coalesced epilogue ----
    {
        const int wave = t >> 6, lane = t & 63;
        const int quad = lane >> 4, fr = lane & 15;
        f32x4 acc[4][4];
        #pragma unroll
        for (int i = 0; i < 4; ++i)
            #pragma unroll
            for (int j = 0; j < 4; ++j) {
                f32x4 z = {0.f, 0.f, 0.f, 0.f};
                acc[i][j] = z;
            }
        #pragma unroll
        for (int kk = 0; kk < 2; ++kk) {
            bfrag af[4], bfr[4];
            #pragma unroll
            for (int i = 0; i < 4; ++i)
                af[i] = *(const bfrag*)&sc_b[16 * i + fr][32 * kk + quad * 8];
            #pragma unroll
            for (int j = 0; j < 4; ++j)
                bfr[j] = *(const bfrag*)&xT[64 * wave + 16 * j + fr][32 * kk + quad * 8];
            #pragma unroll
            for (int i = 0; i < 4; ++i)
                #pragma unroll
                for (int j = 0; j < 4; ++j)
                    acc[i][j] = __builtin_amdgcn_mfma_f32_16x16x32_bf16(
                                    af[i], bfr[j], acc[i][j], 0, 0, 0);
        }
        {   // off-chunk term: K=32 over n (16 real + 16 zero)
            bfrag af[4], bfr[4];
            #pragma unroll
            for (int i = 0; i < 4; ++i)
                af[i] = *(const bfrag*)&A2[16 * i + fr][quad * 8];
            #pragma unroll
            for (int j = 0; j < 4; ++j)
                bfr[j] = *(const bfrag*)&SpT[64 * wave + 16 * j + fr][quad * 8];
            #pragma unroll
            for (int i = 0; i < 4; ++i)
                #pragma unroll
                for (int j = 0; j < 4; ++j)
                    acc[i][j] = __builtin_amdgcn_mfma_f32_16x16x32_bf16(
                                    af[i], bfr[j], acc[i][j], 0, 0, 0);
        }
        __syncthreads();                    // all MFMA reads of xT done
        bf16_t* buf = &xT[0][0];            // reuse as Y[64][264]
        #pragma unroll
        for (int i = 0; i < 4; ++i)
            #pragma unroll
            for (int j = 0; j < 4; ++j) {
                int pc = 64 * wave + 16 * j + fr;
                #pragma unroll
                for (int r = 0; r < 4; ++r) {
                    int l = 16 * i + quad * 4 + r;
                    buf[l * 264 + pc] = f2bf(acc[i][j][r]);
                }
            }
        __syncthreads();
        bf16_t* ybase = &ybuf[(size_t)row0 * DINNER + h * HEADDIM];
        const bf16_t* zbase = &proj[(size_t)row0 * LDP + h * HEADDIM];
        #pragma unroll
        for (int k = 0; k < 8; ++k) {
            int id = k * 256 + t;
            int l = id >> 5, ch = id & 31;
            uint4 yv = *(const uint4*)&buf[l * 264 + ch * 8];
            uint4 zv = *(const uint4*)&zbase[(size_t)l * LDP + ch * 8];
            float ya[8] = {bflo(yv.x), bfhi(yv.x), bflo(yv.y), bfhi(yv.y),
                           bflo(yv.z), bfhi(yv.z), bflo(yv.w), bfhi(yv.w)};
            float za[8] = {bflo(zv.x), bfhi(zv.x), bflo(zv.y), bfhi(zv.y),
                           bflo(zv.z), bfhi(zv.z), bflo(zv.w), bfhi(zv.w)};
            float g[8];
            float ss = 0.f;
            #pragma unroll
            for (int j = 0; j < 8; ++j) {
                float gv = ya[j] * siluf_(za[j]);
                g[j] = gv;
                ss = fmaf(gv, gv, ss);
            }
            uint4 o;
            o.x = pack2(g[0], g[1]); o.y = pack2(g[2], g[3]);
            o.z = pack2(g[4], g[5]); o.w = pack2(g[6], g[7]);
            *(uint4*)&ybase[(size_t)l * DINNER + ch * 8] = o;
            #pragma unroll
            for (int off = 16; off >= 1; off >>= 1) ss += __shfl_xor(ss, off, 32);
            if ((t & 31) == 0) atomicAdd(&rowsum[row0 + l], ss);
        }
    }
}

// ---------------------------------------------------------------------------
extern "C" void kernel_launch(void* const* d_in, const int* in_sizes, int n_in,
                              void* d_out, int out_size, void* d_ws, size_t ws_size,
                              hipStream_t stream)
{
    const float* input   = (const float*)d_in[0];
    const float* W_in    = (const float*)d_in[1];
    const float* conv_w  = (const float*)d_in[2];
    const float* conv_b  = (const float*)d_in[3];
    const float* dt_bias = (const float*)d_in[4];
    const float* log_A   = (const float*)d_in[5];
    const float* D_skip  = (const float*)d_in[6];
    const float* norm_w  = (const float*)d_in[7];
    const float* W_out   = (const float*)d_in[8];
    float* out = (float*)d_out;

    // workspace: proj(138.4MB, stride 4224) | region1 (68.2MB) | Wb2 | rowsum
    // region1: phase-1 = Ab(33.5)+Wb1(8.9, 4352 rows); phase-2 = ybuf (67.1MB)
    bf16_t* proj  = (bf16_t*)d_ws;
    bf16_t* region1 = proj + (size_t)ROWS * LDP;
    bf16_t* Wb2   = region1 + (size_t)ROWS * CONVDIM;
    float*  rowsum = (float*)(Wb2 + (size_t)DMODEL * DINNER);
    bf16_t* Ab    = region1;                     // alias (phase 1 only)
    bf16_t* Wb1   = Ab + (size_t)ROWS * DMODEL;  // alias (phase 1 only)
    bf16_t* ybuf  = region1;                     // alias (phase 2)

    size_t need = (size_t)ROWS * LDP * 2 + (size_t)ROWS * CONVDIM * 2
                + (size_t)DMODEL * DINNER * 2 + (size_t)ROWS * 4;
    if (ws_size < need) {
        hipMemsetAsync(d_out, 0, (size_t)out_size * sizeof(float), stream);
        return;
    }

    // 0) bf16 conversions (+ norm_w folded into Wb2); zero rowsum accumulator
    cvt_f32_bf16<<<(ROWS * DMODEL / 8 + 255) / 256, 256, 0, stream>>>(
        input, Ab, ROWS * DMODEL / 8);
    cvt_pad_w1<<<(NPADW * DMODEL / 4 + 255) / 256, 256, 0, stream>>>(W_in, Wb1);
    cvt_w2<<<(DMODEL * DINNER / 4 + 255) / 256, 256, 0, stream>>>(W_out, norm_w, Wb2);
    hipMemsetAsync(rowsum, 0, (size_t)ROWS * sizeof(float), stream);

    // 1) proj = input @ W_in^T  (barrier-light 256^2 MFMA; M=16384, K=1024)
    dim3 g1(NPADW / 256, ROWS / 256);            // 17 x 64 (nwg%8==0)
    gemm_g1<<<g1, 512, 0, stream>>>(Ab, Wb1, proj, nullptr,
                                    LDP, DMODEL, DMODEL, DMODEL, LDP);
    // 2) fused conv+SSD+gate -> ybuf (gated), rowsum = per-row sum(g^2)
    dim3 gs(NCHUNK, NHEADS, BATCH);
    ssd_fused<<<gs, 256, 0, stream>>>(proj, conv_w, conv_b, dt_bias,
                                      log_A, D_skip, ybuf, rowsum);
    // 3) out = g @ (W_out*norm_w)^T * rsqrt(rowsum/D+eps)  (N=1024, K=2048)
    dim3 g2(DMODEL / 256, ROWS / 256);           // 4 x 64 (nwg%8==0)
    gemm_g2<<<g2, 512, 0, stream>>>(ybuf, Wb2, out, rowsum,
                                    DMODEL, DINNER, DINNER, DINNER, DMODEL);
}

// Round 7
// 522.160 us; speedup vs baseline: 1.0397x; 1.0368x over previous
//
#include <hip/hip_runtime.h>
#include <hip/hip_bf16.h>
#include <math.h>

#define BATCH   4
#define SEQLEN  4096
#define DMODEL  1024
#define DSTATE  16
#define DCONV   4
#define NHEADS  8
#define CHUNKSZ 64
#define DINNER  2048
#define HEADDIM 256          // DINNER / NHEADS
#define CONVDIM 2080         // DINNER + 2*DSTATE
#define DPROJ   4136         // 2*DINNER + 2*DSTATE + NHEADS
#define NPADW   4352         // W_in rows padded to multiple of 256 (17 N-tiles)
#define LDP     4224         // proj row stride (8448 B = 64B-aligned rows)
#define ROWS    (BATCH*SEQLEN)   // 16384
#define NCHUNK  (SEQLEN/CHUNKSZ) // 64

typedef unsigned short bf16_t;
typedef __attribute__((ext_vector_type(8))) short bfrag;    // 8 bf16 = 4 VGPRs
typedef __attribute__((ext_vector_type(4))) float f32x4;
typedef __attribute__((ext_vector_type(16))) float f32x16;  // 32x32 accumulator

__device__ __forceinline__ float sigmoidf_(float v) { return 1.0f / (1.0f + __expf(-v)); }
__device__ __forceinline__ float siluf_(float v)    { return v * sigmoidf_(v); }
__device__ __forceinline__ float softplusf_(float v) {
    return fmaxf(v, 0.f) + log1pf(__expf(-fabsf(v)));
}

__device__ __forceinline__ float bf2f(bf16_t u) {
    union { unsigned int i; float f; } v; v.i = ((unsigned int)u) << 16; return v.f;
}
__device__ __forceinline__ float bflo(unsigned int u) {
    union { unsigned int i; float f; } v; v.i = u << 16; return v.f;
}
__device__ __forceinline__ float bfhi(unsigned int u) {
    union { unsigned int i; float f; } v; v.i = u & 0xffff0000u; return v.f;
}
__device__ __forceinline__ bf16_t f2bf(float f) {   // round-to-nearest-even
    unsigned int x = __float_as_uint(f);
    unsigned int r = (x + 0x7fffu + ((x >> 16) & 1u)) >> 16;
    return (bf16_t)r;
}
__device__ __forceinline__ unsigned int pack2(float a, float b) {
    return (unsigned int)f2bf(a) | ((unsigned int)f2bf(b) << 16);
}

__device__ __forceinline__ void async_copy16(const bf16_t* g, bf16_t* l) {
    __builtin_amdgcn_global_load_lds(
        (const __attribute__((address_space(1))) void*)g,
        (__attribute__((address_space(3))) void*)l, 16, 0, 0);
}

#define WAITV(N)  asm volatile("s_waitcnt vmcnt(" #N ")" ::: "memory")
__device__ __forceinline__ void barrier_() {
    __builtin_amdgcn_s_barrier();
    asm volatile("" ::: "memory");
}

// ---------------------------------------------------------------------------
// conversion kernels
// ---------------------------------------------------------------------------
__global__ __launch_bounds__(256)
void cvt_f32_bf16(const float* __restrict__ src, bf16_t* __restrict__ dst, int n8)
{
    int i = blockIdx.x * 256 + threadIdx.x;
    if (i >= n8) return;
    float4 a = *(const float4*)&src[(size_t)i * 8];
    float4 b = *(const float4*)&src[(size_t)i * 8 + 4];
    uint4 o;
    o.x = pack2(a.x, a.y); o.y = pack2(a.z, a.w);
    o.z = pack2(b.x, b.y); o.w = pack2(b.z, b.w);
    *(uint4*)&dst[(size_t)i * 8] = o;
}

// W_in (4136x1024) -> bf16 padded to 4352 rows (zeros)
__global__ __launch_bounds__(256)
void cvt_pad_w1(const float* __restrict__ src, bf16_t* __restrict__ dst)
{
    int i = blockIdx.x * 256 + threadIdx.x;
    if (i >= NPADW * DMODEL / 4) return;
    size_t e = (size_t)i * 4;
    int row = (int)(e >> 10);
    ushort4 o = make_ushort4(0, 0, 0, 0);
    if (row < DPROJ) {
        float4 v = *(const float4*)&src[e];
        o.x = f2bf(v.x); o.y = f2bf(v.y); o.z = f2bf(v.z); o.w = f2bf(v.w);
    }
    *(ushort4*)&dst[e] = o;
}

// Wb2[n][k] = bf16(W_out[n][k] * norm_w[k])  — norm folded into the weight
__global__ __launch_bounds__(256)
void cvt_w2(const float* __restrict__ W, const float* __restrict__ norm_w,
            bf16_t* __restrict__ dst)
{
    int i = blockIdx.x * 256 + threadIdx.x;
    if (i >= DMODEL * DINNER / 4) return;
    size_t e = (size_t)i * 4;
    int k = (int)(e & (DINNER - 1));
    float4 v = *(const float4*)&W[e];
    float4 w = *(const float4*)&norm_w[k];
    ushort4 o;
    o.x = f2bf(v.x * w.x); o.y = f2bf(v.y * w.y);
    o.z = f2bf(v.z * w.z); o.w = f2bf(v.w * w.w);
    *(ushort4*)&dst[e] = o;
}

// ---------------------------------------------------------------------------
// 256x256 MFMA GEMM, barrier-light schedule + 32x32x16 MFMA.
// (unchanged from round 5 — harness-verified)
// ---------------------------------------------------------------------------
__device__ __forceinline__
void ld_a32(bfrag (&a)[4][2], const bf16_t* base, int wm, int lane, int k0)
{
    const int r5 = lane & 31, hi = lane >> 5;
    #pragma unroll
    for (int ks = 0; ks < 2; ++ks)
        #pragma unroll
        for (int rb = 0; rb < 4; ++rb) {
            int row = wm + rb * 32 + r5;
            int chunk = (2 * (k0 + ks) + hi) ^ (row & 7);
            a[rb][ks] = *(const bfrag*)&base[row * 64 + chunk * 8];
        }
}
__device__ __forceinline__
void ld_b32(bfrag (&b)[2][2], const bf16_t* base, int wn, int lane, int k0)
{
    const int r5 = lane & 31, hi = lane >> 5;
    #pragma unroll
    for (int ks = 0; ks < 2; ++ks)
        #pragma unroll
        for (int cb = 0; cb < 2; ++cb) {
            int row = wn + cb * 32 + r5;
            int chunk = (2 * (k0 + ks) + hi) ^ (row & 7);
            b[cb][ks] = *(const bfrag*)&base[row * 64 + chunk * 8];
        }
}
__device__ __forceinline__
void mm16(f32x16 (&acc)[4][2], const bfrag (&a)[4][2], const bfrag (&b)[2][2])
{
    __builtin_amdgcn_s_setprio(1);
    #pragma unroll
    for (int ks = 0; ks < 2; ++ks)
        #pragma unroll
        for (int rb = 0; rb < 4; ++rb)
            #pragma unroll
            for (int cb = 0; cb < 2; ++cb)
                acc[rb][cb] = __builtin_amdgcn_mfma_f32_32x32x16_bf16(
                    a[rb][ks], b[cb][ks], acc[rb][cb], 0, 0, 0);
    __builtin_amdgcn_s_setprio(0);
}

template<bool OUT_BF16>
__device__ __forceinline__
void gemm256_body(const bf16_t* __restrict__ A, const bf16_t* __restrict__ W,
                  void* __restrict__ Cv, const float* __restrict__ rowSum,
                  int Nstore, int K, int lda, int ldw, int ldc)
{
    __shared__ __align__(16) bf16_t smem[65536];   // 128 KiB
    bf16_t* As = smem;            // [2][256][64]
    bf16_t* Ws = smem + 32768;    // [2][256][64]

    const int tid  = threadIdx.x;
    const int wave = tid >> 6, lane = tid & 63;
    const int ln3  = lane >> 3;
    const int cswz = ((lane & 7) ^ ln3) * 8;       // pre-swizzled source column

    const int gx   = gridDim.x;
    const int nwg  = gx * gridDim.y;
    const int flat = blockIdx.y * gx + blockIdx.x;
    const int q8   = nwg >> 3;                     // nwg % 8 == 0 at both call sites
    const int swz  = (flat & 7) * q8 + (flat >> 3);
    const int col0 = (swz % gx) * 256;
    const int row0 = (swz / gx) * 256;

    const int wm = (wave >> 2) * 128, wn = (wave & 3) * 64;

    // staging source pointers: 2 halves x 2 calls each for A and W.
    const bf16_t* gA[2][2];
    const bf16_t* gW[2][2];
    #pragma unroll
    for (int h = 0; h < 2; ++h)
        #pragma unroll
        for (int q = 0; q < 2; ++q) {
            int rA = 128*q + 8*wave + 64*h;
            int rB = 128*q + 64*(wave >> 2) + 8*(wave & 3) + 32*h;
            gA[h][q] = A + (size_t)(row0 + rA + ln3) * lda + cswz;
            gW[h][q] = W + (size_t)(col0 + rB + ln3) * ldw + cswz;
        }

#define STG_A(H, Q, NB, K0S)                                                     \
    async_copy16(gA[H][Q] + (K0S),                                               \
                 &As[(NB)*16384 + (128*(Q) + 8*wave + 64*(H))*64])
#define STG_B(H, Q, NB, K0S)                                                     \
    async_copy16(gW[H][Q] + (K0S),                                               \
                 &Ws[(NB)*16384 + (128*(Q) + 64*(wave>>2) + 8*(wave&3) + 32*(H))*64])

    f32x16 acc[4][2];
    #pragma unroll
    for (int i = 0; i < 4; ++i)
        #pragma unroll
        for (int j = 0; j < 2; ++j)
            #pragma unroll
            for (int r = 0; r < 16; ++r)
                acc[i][j][r] = 0.f;
    bfrag afr[4][2], bfr[2][2];

    // prologue: stage tile 0 into buf 0 (8 calls)
    STG_A(0,0,0,0); STG_A(0,1,0,0); STG_A(1,0,0,0); STG_A(1,1,0,0);
    STG_B(0,0,0,0); STG_B(0,1,0,0); STG_B(1,0,0,0); STG_B(1,1,0,0);

    const int nt = K >> 6;
    for (int t = 0; t < nt; ++t) {
        const int cur = (t & 1) * 16384;
        const int nb  = (t + 1) & 1;
        const int ko  = (t + 1) * 64;
        const bool stg = (t + 1 < nt);
        WAITV(0);        // retire tile t's 8 calls (issued >= 1 tile ago)
        barrier_();      // all waves done reading buf^1 (tile t-1) -> restage ok
        // phase A: ks 0,1
        ld_a32(afr, As + cur, wm, lane, 0);
        ld_b32(bfr, Ws + cur, wn, lane, 0);
        if (stg) { STG_A(0,0,nb,ko); STG_A(0,1,nb,ko);
                   STG_A(1,0,nb,ko); STG_A(1,1,nb,ko); }
        mm16(acc, afr, bfr);
        // phase B: ks 2,3 (no barrier: same buf, disjoint reg refill after use)
        ld_a32(afr, As + cur, wm, lane, 2);
        ld_b32(bfr, Ws + cur, wn, lane, 2);
        if (stg) { STG_B(0,0,nb,ko); STG_B(0,1,nb,ko);
                   STG_B(1,0,nb,ko); STG_B(1,1,nb,ko); }
        mm16(acc, afr, bfr);
    }

#undef STG_A
#undef STG_B

    const int c32 = lane & 31, hi4 = (lane >> 5) * 4;
    if (OUT_BF16) {
        // LDS-staged coalesced epilogue: two 128-row passes through smem[128][264]
        __syncthreads();
        bf16_t* C = (bf16_t*)Cv;
        #pragma unroll
        for (int pass = 0; pass < 2; ++pass) {
            if ((wave >> 2) == pass) {
                #pragma unroll
                for (int rb = 0; rb < 4; ++rb)
                    #pragma unroll
                    for (int cb = 0; cb < 2; ++cb) {
                        int col = wn + cb * 32 + c32;
                        #pragma unroll
                        for (int reg = 0; reg < 16; ++reg) {
                            int rl = rb * 32 + (reg & 3) + 8 * (reg >> 2) + hi4;
                            smem[rl * 264 + col] = f2bf(acc[rb][cb][reg]);
                        }
                    }
            }
            __syncthreads();
            #pragma unroll
            for (int k = 0; k < 8; ++k) {
                int id = k * 512 + tid;
                int rl = id >> 5, ch = id & 31;
                if (col0 + ch * 8 < Nstore) {
                    uint4 v = *(const uint4*)&smem[rl * 264 + ch * 8];
                    *(uint4*)&C[(size_t)(row0 + pass * 128 + rl) * ldc
                                + col0 + ch * 8] = v;
                }
            }
            if (pass == 0) __syncthreads();
        }
    } else {
        // f32 direct stores; RMS scale computed from raw row sum-of-squares
        float* C = (float*)Cv;
        #pragma unroll
        for (int rb = 0; rb < 4; ++rb) {
            float rs[16];
            #pragma unroll
            for (int reg = 0; reg < 16; ++reg) {
                size_t m = (size_t)row0 + wm + rb * 32
                         + (reg & 3) + 8 * (reg >> 2) + hi4;
                rs[reg] = rowSum ? rsqrtf(rowSum[m] * (1.f / DINNER) + 1e-5f) : 1.f;
            }
            #pragma unroll
            for (int cb = 0; cb < 2; ++cb) {
                int n = col0 + wn + cb * 32 + c32;
                if (n < Nstore) {
                    #pragma unroll
                    for (int reg = 0; reg < 16; ++reg) {
                        size_t m = (size_t)row0 + wm + rb * 32
                                 + (reg & 3) + 8 * (reg >> 2) + hi4;
                        C[m * ldc + n] = acc[rb][cb][reg] * rs[reg];
                    }
                }
            }
        }
    }
}

// distinct names for profiler attribution
__global__ __launch_bounds__(512, 2)
void gemm_g1(const bf16_t* __restrict__ A, const bf16_t* __restrict__ W,
             void* __restrict__ Cv, const float* __restrict__ rowSum,
             int Nstore, int K, int lda, int ldw, int ldc)
{ gemm256_body<true>(A, W, Cv, rowSum, Nstore, K, lda, ldw, ldc); }

__global__ __launch_bounds__(512, 2)
void gemm_g2(const bf16_t* __restrict__ A, const bf16_t* __restrict__ W,
             void* __restrict__ Cv, const float* __restrict__ rowSum,
             int Nstore, int K, int lda, int ldw, int ldc)
{ gemm256_body<false>(A, W, Cv, rowSum, Nstore, K, lda, ldw, ldc); }

// ---------------------------------------------------------------------------
// Fused conv+SSD+gate. One block per (chunk, head, batch), 256 threads.
// Sp state (256x16x64 matmul) on MFMA via BpT; gate fused in epilogue.
// (identical to round 6 — resubmitted to disambiguate infra flake)
// ---------------------------------------------------------------------------
__global__ __launch_bounds__(256)
void ssd_fused(const bf16_t* __restrict__ proj, const float* __restrict__ conv_w,
               const float* __restrict__ conv_b, const float* __restrict__ dt_bias,
               const float* __restrict__ log_A, const float* __restrict__ D_skip,
               bf16_t* __restrict__ ybuf, float* __restrict__ rowsum)
{
    __shared__ float Bc[64][16];
    __shared__ float Cc[64][16];
    __shared__ float dtc[64];
    __shared__ float dtp[64];
    __shared__ __align__(16) bf16_t BpT[32][72];    // Bp^T: [n][s]; rows 16..31 zero
    __shared__ __align__(16) bf16_t sc_b[64][72];   // scores
    __shared__ __align__(16) bf16_t xT[256][72];    // x*dt; reused as Y[64][264]
    __shared__ __align__(16) bf16_t SpT[256][32];   // SpT[p][n], n>=16 zero
    __shared__ __align__(16) bf16_t A2[64][32];     // e(l)*C[l][n], n>=16 zero

    const int c = blockIdx.x, h = blockIdx.y, b = blockIdx.z;
    const int t = threadIdx.x;
    const int row0 = b * SEQLEN + c * CHUNKSZ;
    const float a   = -__expf(log_A[h]);
    const float Dsk = D_skip[h];
    const float bias = dt_bias[h];

    // ---- phase A1: cur-chunk B/C conv+silu (all 256 threads) ----
    {
        int s = t >> 2, ch8 = (t & 3) * 8;      // 8 channels of [0,32)
        int l = c * CHUNKSZ + s;
        const bf16_t* base = &proj[(size_t)(row0 + s) * LDP + 4096 + ch8];
        uint4 zz = make_uint4(0, 0, 0, 0);
        uint4 u3 = *(const uint4*)&base[0];
        uint4 u2 = (l >= 1) ? *(const uint4*)&base[-LDP]     : zz;
        uint4 u1 = (l >= 2) ? *(const uint4*)&base[-2 * LDP] : zz;
        uint4 u0 = (l >= 3) ? *(const uint4*)&base[-3 * LDP] : zz;
        float t3[8] = {bflo(u3.x), bfhi(u3.x), bflo(u3.y), bfhi(u3.y),
                       bflo(u3.z), bfhi(u3.z), bflo(u3.w), bfhi(u3.w)};
        float t2[8] = {bflo(u2.x), bfhi(u2.x), bflo(u2.y), bfhi(u2.y),
                       bflo(u2.z), bfhi(u2.z), bflo(u2.w), bfhi(u2.w)};
        float t1[8] = {bflo(u1.x), bfhi(u1.x), bflo(u1.y), bfhi(u1.y),
                       bflo(u1.z), bfhi(u1.z), bflo(u1.w), bfhi(u1.w)};
        float t0[8] = {bflo(u0.x), bfhi(u0.x), bflo(u0.y), bfhi(u0.y),
                       bflo(u0.z), bfhi(u0.z), bflo(u0.w), bfhi(u0.w)};
        #pragma unroll
        for (int j = 0; j < 8; ++j) {
            int ch = ch8 + j;
            float4 w = *(const float4*)&conv_w[(2048 + ch) * 4];
            float av = conv_b[2048 + ch];
            av = fmaf(w.x, t0[j], av);
            av = fmaf(w.y, t1[j], av);
            av = fmaf(w.z, t2[j], av);
            av = fmaf(w.w, t3[j], av);
            float v = siluf_(av);
            if (ch < 16) Bc[s][ch] = v; else Cc[s][ch - 16] = v;
        }
    }
    // ---- phase A2: prev-chunk B conv -> BpT (t<128) | dt + BpT pad (t>=128) --
    if (t < 128) {
        int s = t >> 1, ch8 = (t & 1) * 8;      // 8 channels of [0,16)
        float vout[8];
        #pragma unroll
        for (int j = 0; j < 8; ++j) vout[j] = 0.f;
        if (c > 0) {
            int l = (c - 1) * CHUNKSZ + s;
            const bf16_t* base = &proj[(size_t)(row0 - CHUNKSZ + s) * LDP + 4096 + ch8];
            uint4 zz = make_uint4(0, 0, 0, 0);
            uint4 u3 = *(const uint4*)&base[0];
            uint4 u2 = (l >= 1) ? *(const uint4*)&base[-LDP]     : zz;
            uint4 u1 = (l >= 2) ? *(const uint4*)&base[-2 * LDP] : zz;
            uint4 u0 = (l >= 3) ? *(const uint4*)&base[-3 * LDP] : zz;
            float t3[8] = {bflo(u3.x), bfhi(u3.x), bflo(u3.y), bfhi(u3.y),
                           bflo(u3.z), bfhi(u3.z), bflo(u3.w), bfhi(u3.w)};
            float t2[8] = {bflo(u2.x), bfhi(u2.x), bflo(u2.y), bfhi(u2.y),
                           bflo(u2.z), bfhi(u2.z), bflo(u2.w), bfhi(u2.w)};
            float t1[8] = {bflo(u1.x), bfhi(u1.x), bflo(u1.y), bfhi(u1.y),
                           bflo(u1.z), bfhi(u1.z), bflo(u1.w), bfhi(u1.w)};
            float t0[8] = {bflo(u0.x), bfhi(u0.x), bflo(u0.y), bfhi(u0.y),
                           bflo(u0.z), bfhi(u0.z), bflo(u0.w), bfhi(u0.w)};
            #pragma unroll
            for (int j = 0; j < 8; ++j) {
                int ch = ch8 + j;
                float4 w = *(const float4*)&conv_w[(2048 + ch) * 4];
                float av = conv_b[2048 + ch];
                av = fmaf(w.x, t0[j], av);
                av = fmaf(w.y, t1[j], av);
                av = fmaf(w.z, t2[j], av);
                av = fmaf(w.w, t3[j], av);
                vout[j] = siluf_(av);
            }
        }
        #pragma unroll
        for (int j = 0; j < 8; ++j) BpT[ch8 + j][s] = f2bf(vout[j]);
    } else if (t < 192) {
        int s = t - 128;
        float v = bf2f(proj[(size_t)(row0 + s) * LDP + 4128 + h]) + bias;
        dtc[s] = softplusf_(v);
    } else {
        int s = t - 192;
        float w = 0.f;
        if (c > 0) {
            float v = bf2f(proj[(size_t)(row0 - CHUNKSZ + s) * LDP + 4128 + h]) + bias;
            w = softplusf_(v) * __expf(a * (float)(63 - s));   // fold decay_states
        }
        dtp[s] = w;
        // zero BpT pad rows 16..31 over s columns 0..63 (64 threads x 16 bf16)
        int idx = t - 192;
        int zr = 16 + (idx >> 2), zc = (idx & 3) * 16;
        uint4 zz = make_uint4(0, 0, 0, 0);
        *(uint4*)&BpT[zr][zc]     = zz;
        *(uint4*)&BpT[zr][zc + 8] = zz;
    }
    __syncthreads();

    // ---- phase B: scores -> sc_b (bf16); A2 rows ----
    {
        int l = t >> 2;
        int sbase = (t & 3) * 16;
        unsigned int pk[8];
        #pragma unroll
        for (int jj = 0; jj < 16; jj += 2) {
            float v0 = 0.f, v1 = 0.f;
            int s0 = sbase + jj, s1 = s0 + 1;
            if (s0 <= l) {
                float dot = 0.f;
                #pragma unroll
                for (int n = 0; n < 16; ++n) dot = fmaf(Cc[l][n], Bc[s0][n], dot);
                v0 = dot * __expf(a * (float)(l - s0));
                if (s0 == l) v0 += Dsk;
            }
            if (s1 <= l) {
                float dot = 0.f;
                #pragma unroll
                for (int n = 0; n < 16; ++n) dot = fmaf(Cc[l][n], Bc[s1][n], dot);
                v1 = dot * __expf(a * (float)(l - s1));
                if (s1 == l) v1 += Dsk;
            }
            pk[jj >> 1] = pack2(v0, v1);
        }
        uint4 u0 = {pk[0], pk[1], pk[2], pk[3]};
        uint4 u1 = {pk[4], pk[5], pk[6], pk[7]};
        *(uint4*)&sc_b[l][sbase]     = u0;
        *(uint4*)&sc_b[l][sbase + 8] = u1;
    }
    if (t < 64) {   // A2[t][n] = bf16(exp(a(t+1)) * Cc[t][n]); n>=16 zero
        float e = __expf(a * (float)(t + 1));
        unsigned int pk[8];
        #pragma unroll
        for (int n = 0; n < 16; n += 2) pk[n >> 1] = pack2(e * Cc[t][n], e * Cc[t][n + 1]);
        uint4 u0 = {pk[0], pk[1], pk[2], pk[3]};
        uint4 u1 = {pk[4], pk[5], pk[6], pk[7]};
        uint4 zz = make_uint4(0, 0, 0, 0);
        *(uint4*)&A2[t][0]  = u0;
        *(uint4*)&A2[t][8]  = u1;
        *(uint4*)&A2[t][16] = zz;
        *(uint4*)&A2[t][24] = zz;
    }

    // ---- phase C: prev conv -> xT -> Sp(MFMA) -> SpT; then cur conv -> xT ----
    {
        const int p = t;
        const int wave = t >> 6, lane = t & 63;
        const int r5 = lane & 31, hi = lane >> 5;
        const int xch = h * HEADDIM + p;          // x channel 0..2047
        const float4 w = *(const float4*)&conv_w[(size_t)xch * 4];
        const float cb = conv_b[xch];
        const int colp = 2048 + xch;              // proj column

        // C1: previous chunk conv * dtp -> xT[p][s]  (zeros when c == 0)
        if (c > 0) {
            const bf16_t* pr = &proj[(size_t)(row0 - CHUNKSZ) * LDP + colp];
            int l0 = (c - 1) * CHUNKSZ;
            float xm3 = (l0 >= 3) ? bf2f(pr[-3 * LDP]) : 0.f;
            float xm2 = (l0 >= 2) ? bf2f(pr[-2 * LDP]) : 0.f;
            float xm1 = (l0 >= 1) ? bf2f(pr[-LDP])     : 0.f;
            #pragma unroll
            for (int s0 = 0; s0 < 64; s0 += 8) {
                float xd[8];
                #pragma unroll
                for (int q = 0; q < 8; ++q) {
                    float xc = bf2f(pr[(size_t)(s0 + q) * LDP]);
                    float av = cb;
                    av = fmaf(w.x, xm3, av);
                    av = fmaf(w.y, xm2, av);
                    av = fmaf(w.z, xm1, av);
                    av = fmaf(w.w, xc, av);
                    xd[q] = siluf_(av) * dtp[s0 + q];
                    xm3 = xm2; xm2 = xm1; xm1 = xc;
                }
                uint4 u;
                u.x = pack2(xd[0], xd[1]); u.y = pack2(xd[2], xd[3]);
                u.z = pack2(xd[4], xd[5]); u.w = pack2(xd[6], xd[7]);
                *(uint4*)&xT[p][s0] = u;
            }
        } else {
            uint4 zz = make_uint4(0, 0, 0, 0);
            #pragma unroll
            for (int s0 = 0; s0 < 64; s0 += 8) *(uint4*)&xT[p][s0] = zz;
        }

        // C2: Sp[p][n] = sum_s xT[p][s] * BpT[n][s] via MFMA.
        // Wave-local: A-frag rows are this wave's own 64 xT rows (written by
        // this wave's lanes above -> in-wave lgkm ordering suffices, no
        // barrier). BpT written pre-barrier in phase A2.
        {
            f32x16 sacc[2];
            #pragma unroll
            for (int rb = 0; rb < 2; ++rb)
                #pragma unroll
                for (int r = 0; r < 16; ++r) sacc[rb][r] = 0.f;
            #pragma unroll
            for (int ks = 0; ks < 4; ++ks) {
                bfrag bb = *(const bfrag*)&BpT[r5][ks * 16 + hi * 8];
                #pragma unroll
                for (int rb = 0; rb < 2; ++rb) {
                    bfrag aa = *(const bfrag*)
                        &xT[64 * wave + rb * 32 + r5][ks * 16 + hi * 8];
                    sacc[rb] = __builtin_amdgcn_mfma_f32_32x32x16_bf16(
                                   aa, bb, sacc[rb], 0, 0, 0);
                }
            }
            #pragma unroll
            for (int rb = 0; rb < 2; ++rb)
                #pragma unroll
                for (int reg = 0; reg < 16; ++reg) {
                    int pr_ = 64 * wave + rb * 32
                            + (reg & 3) + 8 * (reg >> 2) + 4 * hi;
                    SpT[pr_][r5] = f2bf(sacc[rb][reg]);   // n>=16 cols get 0
                }
        }

        // C3: current chunk conv * dtc -> xT[p][s] (overwrite; wave-local rows,
        // ordered after C2's frag reads by in-wave LDS ordering)
        {
            const bf16_t* pr = &proj[(size_t)row0 * LDP + colp];
            int l0 = c * CHUNKSZ;
            float xm3 = (l0 >= 3) ? bf2f(pr[-3 * LDP]) : 0.f;
            float xm2 = (l0 >= 2) ? bf2f(pr[-2 * LDP]) : 0.f;
            float xm1 = (l0 >= 1) ? bf2f(pr[-LDP])     : 0.f;
            #pragma unroll
            for (int s0 = 0; s0 < 64; s0 += 8) {
                float xd[8];
                #pragma unroll
                for (int q = 0; q < 8; ++q) {
                    float xc = bf2f(pr[(size_t)(s0 + q) * LDP]);
                    float av = cb;
                    av = fmaf(w.x, xm3, av);
                    av = fmaf(w.y, xm2, av);
                    av = fmaf(w.z, xm1, av);
                    av = fmaf(w.w, xc, av);
                    xd[q] = siluf_(av) * dtc[s0 + q];
                    xm3 = xm2; xm2 = xm1; xm1 = xc;
                }
                uint4 u;
                u.x = pack2(xd[0], xd[1]); u.y = pack2(xd[2], xd[3]);
                u.z = pack2(xd[4], xd[5]); u.w = pack2(xd[6], xd[7]);
                *(uint4*)&xT[p][s0] = u;
            }
        }
    }
    __syncthreads();

    // ---- phase D: MFMA + gated coalesced epilogue ----
    {
        const int wave = t >> 6, lane = t & 63;
        const int quad = lane >> 4, fr = lane & 15;
        f32x4 acc[4][4];
        #pragma unroll
        for (int i = 0; i < 4; ++i)
            #pragma unroll
            for (int j = 0; j < 4; ++j) {
                f32x4 z = {0.f, 0.f, 0.f, 0.f};
                acc[i][j] = z;
            }
        #pragma unroll
        for (int kk = 0; kk < 2; ++kk) {
            bfrag af[4], bfr[4];
            #pragma unroll
            for (int i = 0; i < 4; ++i)
                af[i] = *(const bfrag*)&sc_b[16 * i + fr][32 * kk + quad * 8];
            #pragma unroll
            for (int j = 0; j < 4; ++j)
                bfr[j] = *(const bfrag*)&xT[64 * wave + 16 * j + fr][32 * kk + quad * 8];
            #pragma unroll
            for (int i = 0; i < 4; ++i)
                #pragma unroll
                for (int j = 0; j < 4; ++j)
                    acc[i][j] = __builtin_amdgcn_mfma_f32_16x16x32_bf16(
                                    af[i], bfr[j], acc[i][j], 0, 0, 0);
        }
        {   // off-chunk term: K=32 over n (16 real + 16 zero)
            bfrag af[4], bfr[4];
            #pragma unroll
            for (int i = 0; i < 4; ++i)
                af[i] = *(const bfrag*)&A2[16 * i + fr][quad * 8];
            #pragma unroll
            for (int j = 0; j < 4; ++j)
                bfr[j] = *(const bfrag*)&SpT[64 * wave + 16 * j + fr][quad * 8];
            #pragma unroll
            for (int i = 0; i < 4; ++i)
                #pragma unroll
                for (int j = 0; j < 4; ++j)
                    acc[i][j] = __builtin_amdgcn_mfma_f32_16x16x32_bf16(
                                    af[i], bfr[j], acc[i][j], 0, 0, 0);
        }
        __syncthreads();                    // all MFMA reads of xT done
        bf16_t* buf = &xT[0][0];            // reuse as Y[64][264]
        #pragma unroll
        for (int i = 0; i < 4; ++i)
            #pragma unroll
            for (int j = 0; j < 4; ++j) {
                int pc = 64 * wave + 16 * j + fr;
                #pragma unroll
                for (int r = 0; r < 4; ++r) {
                    int l = 16 * i + quad * 4 + r;
                    buf[l * 264 + pc] = f2bf(acc[i][j][r]);
                }
            }
        __syncthreads();
        bf16_t* ybase = &ybuf[(size_t)row0 * DINNER + h * HEADDIM];
        const bf16_t* zbase = &proj[(size_t)row0 * LDP + h * HEADDIM];
        #pragma unroll
        for (int k = 0; k < 8; ++k) {
            int id = k * 256 + t;
            int l = id >> 5, ch = id & 31;
            uint4 yv = *(const uint4*)&buf[l * 264 + ch * 8];
            uint4 zv = *(const uint4*)&zbase[(size_t)l * LDP + ch * 8];
            float ya[8] = {bflo(yv.x), bfhi(yv.x), bflo(yv.y), bfhi(yv.y),
                           bflo(yv.z), bfhi(yv.z), bflo(yv.w), bfhi(yv.w)};
            float za[8] = {bflo(zv.x), bfhi(zv.x), bflo(zv.y), bfhi(zv.y),
                           bflo(zv.z), bfhi(zv.z), bflo(zv.w), bfhi(zv.w)};
            float g[8];
            float ss = 0.f;
            #pragma unroll
            for (int j = 0; j < 8; ++j) {
                float gv = ya[j] * siluf_(za[j]);
                g[j] = gv;
                ss = fmaf(gv, gv, ss);
            }
            uint4 o;
            o.x = pack2(g[0], g[1]); o.y = pack2(g[2], g[3]);
            o.z = pack2(g[4], g[5]); o.w = pack2(g[6], g[7]);
            *(uint4*)&ybase[(size_t)l * DINNER + ch * 8] = o;
            #pragma unroll
            for (int off = 16; off >= 1; off >>= 1) ss += __shfl_xor(ss, off, 32);
            if ((t & 31) == 0) atomicAdd(&rowsum[row0 + l], ss);
        }
    }
}

// ---------------------------------------------------------------------------
extern "C" void kernel_launch(void* const* d_in, const int* in_sizes, int n_in,
                              void* d_out, int out_size, void* d_ws, size_t ws_size,
                              hipStream_t stream)
{
    const float* input   = (const float*)d_in[0];
    const float* W_in    = (const float*)d_in[1];
    const float* conv_w  = (const float*)d_in[2];
    const float* conv_b  = (const float*)d_in[3];
    const float* dt_bias = (const float*)d_in[4];
    const float* log_A   = (const float*)d_in[5];
    const float* D_skip  = (const float*)d_in[6];
    const float* norm_w  = (const float*)d_in[7];
    const float* W_out   = (const float*)d_in[8];
    float* out = (float*)d_out;

    // workspace: proj(138.4MB, stride 4224) | region1 (68.2MB) | Wb2 | rowsum
    // region1: phase-1 = Ab(33.5)+Wb1(8.9, 4352 rows); phase-2 = ybuf (67.1MB)
    bf16_t* proj  = (bf16_t*)d_ws;
    bf16_t* region1 = proj + (size_t)ROWS * LDP;
    bf16_t* Wb2   = region1 + (size_t)ROWS * CONVDIM;
    float*  rowsum = (float*)(Wb2 + (size_t)DMODEL * DINNER);
    bf16_t* Ab    = region1;                     // alias (phase 1 only)
    bf16_t* Wb1   = Ab + (size_t)ROWS * DMODEL;  // alias (phase 1 only)
    bf16_t* ybuf  = region1;                     // alias (phase 2)

    size_t need = (size_t)ROWS * LDP * 2 + (size_t)ROWS * CONVDIM * 2
                + (size_t)DMODEL * DINNER * 2 + (size_t)ROWS * 4;
    if (ws_size < need) {
        hipMemsetAsync(d_out, 0, (size_t)out_size * sizeof(float), stream);
        return;
    }

    // 0) bf16 conversions (+ norm_w folded into Wb2); zero rowsum accumulator
    cvt_f32_bf16<<<(ROWS * DMODEL / 8 + 255) / 256, 256, 0, stream>>>(
        input, Ab, ROWS * DMODEL / 8);
    cvt_pad_w1<<<(NPADW * DMODEL / 4 + 255) / 256, 256, 0, stream>>>(W_in, Wb1);
    cvt_w2<<<(DMODEL * DINNER / 4 + 255) / 256, 256, 0, stream>>>(W_out, norm_w, Wb2);
    hipMemsetAsync(rowsum, 0, (size_t)ROWS * sizeof(float), stream);

    // 1) proj = input @ W_in^T  (barrier-light 256^2 MFMA; M=16384, K=1024)
    dim3 g1(NPADW / 256, ROWS / 256);            // 17 x 64 (nwg%8==0)
    gemm_g1<<<g1, 512, 0, stream>>>(Ab, Wb1, proj, nullptr,
                                    LDP, DMODEL, DMODEL, DMODEL, LDP);
    // 2) fused conv+SSD+gate -> ybuf (gated), rowsum = per-row sum(g^2)
    dim3 gs(NCHUNK, NHEADS, BATCH);
    ssd_fused<<<gs, 256, 0, stream>>>(proj, conv_w, conv_b, dt_bias,
                                      log_A, D_skip, ybuf, rowsum);
    // 3) out = g @ (W_out*norm_w)^T * rsqrt(rowsum/D+eps)  (N=1024, K=2048)
    dim3 g2(DMODEL / 256, ROWS / 256);           // 4 x 64 (nwg%8==0)
    gemm_g2<<<g2, 512, 0, stream>>>(ybuf, Wb2, out, rowsum,
                                    DMODEL, DINNER, DINNER, DINNER, DMODEL);
}

// Round 8
// 518.828 us; speedup vs baseline: 1.0464x; 1.0064x over previous
//
#include <hip/hip_runtime.h>
#include <hip/hip_bf16.h>
#include <math.h>

#define BATCH   4
#define SEQLEN  4096
#define DMODEL  1024
#define DSTATE  16
#define DCONV   4
#define NHEADS  8
#define CHUNKSZ 64
#define DINNER  2048
#define HEADDIM 256          // DINNER / NHEADS
#define CONVDIM 2080         // DINNER + 2*DSTATE
#define DPROJ   4136         // 2*DINNER + 2*DSTATE + NHEADS
#define NPADW   4352         // W_in rows padded to multiple of 256 (17 N-tiles)
#define LDP     4224         // proj row stride (8448 B = 64B-aligned rows)
#define ROWS    (BATCH*SEQLEN)   // 16384
#define NCHUNK  (SEQLEN/CHUNKSZ) // 64

typedef unsigned short bf16_t;
typedef __attribute__((ext_vector_type(8))) short bfrag;    // 8 bf16 = 4 VGPRs
typedef __attribute__((ext_vector_type(4))) float f32x4;
typedef __attribute__((ext_vector_type(16))) float f32x16;  // 32x32 accumulator

__device__ __forceinline__ float sigmoidf_(float v) { return 1.0f / (1.0f + __expf(-v)); }
__device__ __forceinline__ float siluf_(float v)    { return v * sigmoidf_(v); }
__device__ __forceinline__ float softplusf_(float v) {
    return fmaxf(v, 0.f) + log1pf(__expf(-fabsf(v)));
}

__device__ __forceinline__ float bf2f(bf16_t u) {
    union { unsigned int i; float f; } v; v.i = ((unsigned int)u) << 16; return v.f;
}
__device__ __forceinline__ float bflo(unsigned int u) {
    union { unsigned int i; float f; } v; v.i = u << 16; return v.f;
}
__device__ __forceinline__ float bfhi(unsigned int u) {
    union { unsigned int i; float f; } v; v.i = u & 0xffff0000u; return v.f;
}
__device__ __forceinline__ bf16_t f2bf(float f) {   // round-to-nearest-even
    unsigned int x = __float_as_uint(f);
    unsigned int r = (x + 0x7fffu + ((x >> 16) & 1u)) >> 16;
    return (bf16_t)r;
}
__device__ __forceinline__ unsigned int pack2(float a, float b) {
    return (unsigned int)f2bf(a) | ((unsigned int)f2bf(b) << 16);
}

__device__ __forceinline__ void async_copy16(const bf16_t* g, bf16_t* l) {
    __builtin_amdgcn_global_load_lds(
        (const __attribute__((address_space(1))) void*)g,
        (__attribute__((address_space(3))) void*)l, 16, 0, 0);
}

#define WAITV(N)  asm volatile("s_waitcnt vmcnt(" #N ")" ::: "memory")
__device__ __forceinline__ void barrier_() {
    __builtin_amdgcn_s_barrier();
    asm volatile("" ::: "memory");
}

// ---------------------------------------------------------------------------
// conversion kernels
// ---------------------------------------------------------------------------
__global__ __launch_bounds__(256)
void cvt_f32_bf16(const float* __restrict__ src, bf16_t* __restrict__ dst, int n8)
{
    int i = blockIdx.x * 256 + threadIdx.x;
    if (i >= n8) return;
    float4 a = *(const float4*)&src[(size_t)i * 8];
    float4 b = *(const float4*)&src[(size_t)i * 8 + 4];
    uint4 o;
    o.x = pack2(a.x, a.y); o.y = pack2(a.z, a.w);
    o.z = pack2(b.x, b.y); o.w = pack2(b.z, b.w);
    *(uint4*)&dst[(size_t)i * 8] = o;
}

// W_in (4136x1024) -> bf16 padded to 4352 rows (zeros)
__global__ __launch_bounds__(256)
void cvt_pad_w1(const float* __restrict__ src, bf16_t* __restrict__ dst)
{
    int i = blockIdx.x * 256 + threadIdx.x;
    if (i >= NPADW * DMODEL / 4) return;
    size_t e = (size_t)i * 4;
    int row = (int)(e >> 10);
    ushort4 o = make_ushort4(0, 0, 0, 0);
    if (row < DPROJ) {
        float4 v = *(const float4*)&src[e];
        o.x = f2bf(v.x); o.y = f2bf(v.y); o.z = f2bf(v.z); o.w = f2bf(v.w);
    }
    *(ushort4*)&dst[e] = o;
}

// Wb2[n][k] = bf16(W_out[n][k] * norm_w[k])  — norm folded into the weight
__global__ __launch_bounds__(256)
void cvt_w2(const float* __restrict__ W, const float* __restrict__ norm_w,
            bf16_t* __restrict__ dst)
{
    int i = blockIdx.x * 256 + threadIdx.x;
    if (i >= DMODEL * DINNER / 4) return;
    size_t e = (size_t)i * 4;
    int k = (int)(e & (DINNER - 1));
    float4 v = *(const float4*)&W[e];
    float4 w = *(const float4*)&norm_w[k];
    ushort4 o;
    o.x = f2bf(v.x * w.x); o.y = f2bf(v.y * w.y);
    o.z = f2bf(v.z * w.z); o.w = f2bf(v.w * w.w);
    *(ushort4*)&dst[e] = o;
}

// ---------------------------------------------------------------------------
// 256x256 MFMA GEMM: barrier-light schedule (round 5/7, verified) combined
// with the 16x16x32 conflict-free fragment reads (rounds 1-3, verified, 0
// bank conflicts). The 32x32 frag read was a 4-way bank conflict (13.4M
// cycles/dispatch): 32 consecutive rows x same 16B chunk on a 128B-stride
// row-major tile; chunk^(row&7) only separates 8 row classes. The 16x16
// pattern (16 rows x quad-XOR chunks) measured 0 conflicts on this layout.
// Per K-tile (BK=64): ONE vmcnt(0)+barrier, then two free-running phases:
//   {ld af[8],bf[4] for k 0..31 | stage t+1 A-halves -> buf^1 | 32 MFMA}
//   {ld af[8],bf[4] for k 32..63 | stage t+1 B-halves -> buf^1 | 32 MFMA}
// Staging only targets the INACTIVE buffer (no in-buffer hazards).
// ---------------------------------------------------------------------------
__device__ __forceinline__
void ld_af8(bfrag (&af)[8], const bf16_t* base, int wm, int fr, int quad, int kk)
{
    #pragma unroll
    for (int i = 0; i < 8; ++i)
        af[i] = *(const bfrag*)
            &base[(wm + i*16 + fr)*64 + (((kk*4 + quad) ^ (fr & 7)) * 8)];
}
__device__ __forceinline__
void ld_bf4(bfrag (&bf_)[4], const bf16_t* base, int wn, int fr, int quad, int kk)
{
    #pragma unroll
    for (int j = 0; j < 4; ++j)
        bf_[j] = *(const bfrag*)
            &base[(wn + j*16 + fr)*64 + (((kk*4 + quad) ^ (fr & 7)) * 8)];
}
__device__ __forceinline__
void mma32(f32x4 (&acc)[8][4], const bfrag (&af)[8], const bfrag (&bf_)[4])
{
    __builtin_amdgcn_s_setprio(1);
    #pragma unroll
    for (int i = 0; i < 8; ++i)
        #pragma unroll
        for (int j = 0; j < 4; ++j)
            acc[i][j] = __builtin_amdgcn_mfma_f32_16x16x32_bf16(
                af[i], bf_[j], acc[i][j], 0, 0, 0);
    __builtin_amdgcn_s_setprio(0);
}

template<bool OUT_BF16>
__device__ __forceinline__
void gemm256_body(const bf16_t* __restrict__ A, const bf16_t* __restrict__ W,
                  void* __restrict__ Cv, const float* __restrict__ rowSum,
                  int Nstore, int K, int lda, int ldw, int ldc)
{
    __shared__ __align__(16) bf16_t smem[65536];   // 128 KiB
    bf16_t* As = smem;            // [2][256][64]
    bf16_t* Ws = smem + 32768;    // [2][256][64]

    const int tid  = threadIdx.x;
    const int wave = tid >> 6, lane = tid & 63;
    const int quad = lane >> 4, fr = lane & 15;
    const int ln3  = lane >> 3;
    const int cswz = ((lane & 7) ^ ln3) * 8;       // pre-swizzled source column

    const int gx   = gridDim.x;
    const int nwg  = gx * gridDim.y;
    const int flat = blockIdx.y * gx + blockIdx.x;
    const int q8   = nwg >> 3;                     // nwg % 8 == 0 at both call sites
    const int swz  = (flat & 7) * q8 + (flat >> 3);
    const int col0 = (swz % gx) * 256;
    const int row0 = (swz / gx) * 256;

    const int wm = (wave >> 2) * 128, wn = (wave & 3) * 64;

    // staging source pointers: 2 halves x 2 calls each for A and W.
    const bf16_t* gA[2][2];
    const bf16_t* gW[2][2];
    #pragma unroll
    for (int h = 0; h < 2; ++h)
        #pragma unroll
        for (int q = 0; q < 2; ++q) {
            int rA = 128*q + 8*wave + 64*h;
            int rB = 128*q + 64*(wave >> 2) + 8*(wave & 3) + 32*h;
            gA[h][q] = A + (size_t)(row0 + rA + ln3) * lda + cswz;
            gW[h][q] = W + (size_t)(col0 + rB + ln3) * ldw + cswz;
        }

#define STG_A(H, Q, NB, K0S)                                                     \
    async_copy16(gA[H][Q] + (K0S),                                               \
                 &As[(NB)*16384 + (128*(Q) + 8*wave + 64*(H))*64])
#define STG_B(H, Q, NB, K0S)                                                     \
    async_copy16(gW[H][Q] + (K0S),                                               \
                 &Ws[(NB)*16384 + (128*(Q) + 64*(wave>>2) + 8*(wave&3) + 32*(H))*64])

    f32x4 acc[8][4];
    #pragma unroll
    for (int i = 0; i < 8; ++i)
        #pragma unroll
        for (int j = 0; j < 4; ++j) {
            f32x4 z = {0.f, 0.f, 0.f, 0.f};
            acc[i][j] = z;
        }
    bfrag af[8], bf_[4];

    // prologue: stage tile 0 into buf 0 (8 calls)
    STG_A(0,0,0,0); STG_A(0,1,0,0); STG_A(1,0,0,0); STG_A(1,1,0,0);
    STG_B(0,0,0,0); STG_B(0,1,0,0); STG_B(1,0,0,0); STG_B(1,1,0,0);

    const int nt = K >> 6;
    for (int t = 0; t < nt; ++t) {
        const int cur = (t & 1) * 16384;
        const int nb  = (t + 1) & 1;
        const int ko  = (t + 1) * 64;
        const bool stg = (t + 1 < nt);
        WAITV(0);        // retire tile t's 8 calls (issued >= 1 tile ago)
        barrier_();      // all waves done reading buf^1 (tile t-1) -> restage ok
        // phase A: k 0..31 (kk=0)
        ld_af8(af, As + cur, wm, fr, quad, 0);
        ld_bf4(bf_, Ws + cur, wn, fr, quad, 0);
        if (stg) { STG_A(0,0,nb,ko); STG_A(0,1,nb,ko);
                   STG_A(1,0,nb,ko); STG_A(1,1,nb,ko); }
        mma32(acc, af, bf_);
        // phase B: k 32..63 (kk=1); same buf, reg refill strictly after use
        ld_af8(af, As + cur, wm, fr, quad, 1);
        ld_bf4(bf_, Ws + cur, wn, fr, quad, 1);
        if (stg) { STG_B(0,0,nb,ko); STG_B(0,1,nb,ko);
                   STG_B(1,0,nb,ko); STG_B(1,1,nb,ko); }
        mma32(acc, af, bf_);
    }

#undef STG_A
#undef STG_B

    if (OUT_BF16) {
        // LDS-staged coalesced epilogue: two 128-row passes through smem[128][264]
        __syncthreads();
        bf16_t* C = (bf16_t*)Cv;
        #pragma unroll
        for (int pass = 0; pass < 2; ++pass) {
            if ((wave >> 2) == pass) {
                #pragma unroll
                for (int i = 0; i < 8; ++i)
                    #pragma unroll
                    for (int j = 0; j < 4; ++j) {
                        int col = wn + 16 * j + fr;
                        #pragma unroll
                        for (int r = 0; r < 4; ++r) {
                            int rl = 16 * i + quad * 4 + r;
                            smem[rl * 264 + col] = f2bf(acc[i][j][r]);
                        }
                    }
            }
            __syncthreads();
            #pragma unroll
            for (int k = 0; k < 8; ++k) {
                int id = k * 512 + tid;
                int rl = id >> 5, ch = id & 31;
                if (col0 + ch * 8 < Nstore) {
                    uint4 v = *(const uint4*)&smem[rl * 264 + ch * 8];
                    *(uint4*)&C[(size_t)(row0 + pass * 128 + rl) * ldc
                                + col0 + ch * 8] = v;
                }
            }
            if (pass == 0) __syncthreads();
        }
    } else {
        // f32 direct stores; RMS scale computed from raw row sum-of-squares
        float* C = (float*)Cv;
        #pragma unroll
        for (int i = 0; i < 8; ++i) {
            float rs4[4];
            #pragma unroll
            for (int r = 0; r < 4; ++r) {
                size_t m = (size_t)row0 + wm + 16 * i + quad * 4 + r;
                rs4[r] = rowSum ? rsqrtf(rowSum[m] * (1.f / DINNER) + 1e-5f) : 1.f;
            }
            #pragma unroll
            for (int j = 0; j < 4; ++j) {
                int n = col0 + wn + 16 * j + fr;
                if (n < Nstore) {
                    #pragma unroll
                    for (int r = 0; r < 4; ++r) {
                        size_t m = (size_t)row0 + wm + 16 * i + quad * 4 + r;
                        C[m * ldc + n] = acc[i][j][r] * rs4[r];
                    }
                }
            }
        }
    }
}

// distinct names for profiler attribution
__global__ __launch_bounds__(512, 2)
void gemm_g1(const bf16_t* __restrict__ A, const bf16_t* __restrict__ W,
             void* __restrict__ Cv, const float* __restrict__ rowSum,
             int Nstore, int K, int lda, int ldw, int ldc)
{ gemm256_body<true>(A, W, Cv, rowSum, Nstore, K, lda, ldw, ldc); }

__global__ __launch_bounds__(512, 2)
void gemm_g2(const bf16_t* __restrict__ A, const bf16_t* __restrict__ W,
             void* __restrict__ Cv, const float* __restrict__ rowSum,
             int Nstore, int K, int lda, int ldw, int ldc)
{ gemm256_body<false>(A, W, Cv, rowSum, Nstore, K, lda, ldw, ldc); }

// ---------------------------------------------------------------------------
// Fused conv+SSD+gate. One block per (chunk, head, batch), 256 threads.
// Sp state (256x16x64 matmul) on MFMA via BpT; gate fused in epilogue.
// (identical to round 7 — harness-verified)
// ---------------------------------------------------------------------------
__global__ __launch_bounds__(256)
void ssd_fused(const bf16_t* __restrict__ proj, const float* __restrict__ conv_w,
               const float* __restrict__ conv_b, const float* __restrict__ dt_bias,
               const float* __restrict__ log_A, const float* __restrict__ D_skip,
               bf16_t* __restrict__ ybuf, float* __restrict__ rowsum)
{
    __shared__ float Bc[64][16];
    __shared__ float Cc[64][16];
    __shared__ float dtc[64];
    __shared__ float dtp[64];
    __shared__ __align__(16) bf16_t BpT[32][72];    // Bp^T: [n][s]; rows 16..31 zero
    __shared__ __align__(16) bf16_t sc_b[64][72];   // scores
    __shared__ __align__(16) bf16_t xT[256][72];    // x*dt; reused as Y[64][264]
    __shared__ __align__(16) bf16_t SpT[256][32];   // SpT[p][n], n>=16 zero
    __shared__ __align__(16) bf16_t A2[64][32];     // e(l)*C[l][n], n>=16 zero

    const int c = blockIdx.x, h = blockIdx.y, b = blockIdx.z;
    const int t = threadIdx.x;
    const int row0 = b * SEQLEN + c * CHUNKSZ;
    const float a   = -__expf(log_A[h]);
    const float Dsk = D_skip[h];
    const float bias = dt_bias[h];

    // ---- phase A1: cur-chunk B/C conv+silu (all 256 threads) ----
    {
        int s = t >> 2, ch8 = (t & 3) * 8;      // 8 channels of [0,32)
        int l = c * CHUNKSZ + s;
        const bf16_t* base = &proj[(size_t)(row0 + s) * LDP + 4096 + ch8];
        uint4 zz = make_uint4(0, 0, 0, 0);
        uint4 u3 = *(const uint4*)&base[0];
        uint4 u2 = (l >= 1) ? *(const uint4*)&base[-LDP]     : zz;
        uint4 u1 = (l >= 2) ? *(const uint4*)&base[-2 * LDP] : zz;
        uint4 u0 = (l >= 3) ? *(const uint4*)&base[-3 * LDP] : zz;
        float t3[8] = {bflo(u3.x), bfhi(u3.x), bflo(u3.y), bfhi(u3.y),
                       bflo(u3.z), bfhi(u3.z), bflo(u3.w), bfhi(u3.w)};
        float t2[8] = {bflo(u2.x), bfhi(u2.x), bflo(u2.y), bfhi(u2.y),
                       bflo(u2.z), bfhi(u2.z), bflo(u2.w), bfhi(u2.w)};
        float t1[8] = {bflo(u1.x), bfhi(u1.x), bflo(u1.y), bfhi(u1.y),
                       bflo(u1.z), bfhi(u1.z), bflo(u1.w), bfhi(u1.w)};
        float t0[8] = {bflo(u0.x), bfhi(u0.x), bflo(u0.y), bfhi(u0.y),
                       bflo(u0.z), bfhi(u0.z), bflo(u0.w), bfhi(u0.w)};
        #pragma unroll
        for (int j = 0; j < 8; ++j) {
            int ch = ch8 + j;
            float4 w = *(const float4*)&conv_w[(2048 + ch) * 4];
            float av = conv_b[2048 + ch];
            av = fmaf(w.x, t0[j], av);
            av = fmaf(w.y, t1[j], av);
            av = fmaf(w.z, t2[j], av);
            av = fmaf(w.w, t3[j], av);
            float v = siluf_(av);
            if (ch < 16) Bc[s][ch] = v; else Cc[s][ch - 16] = v;
        }
    }
    // ---- phase A2: prev-chunk B conv -> BpT (t<128) | dt + BpT pad (t>=128) --
    if (t < 128) {
        int s = t >> 1, ch8 = (t & 1) * 8;      // 8 channels of [0,16)
        float vout[8];
        #pragma unroll
        for (int j = 0; j < 8; ++j) vout[j] = 0.f;
        if (c > 0) {
            int l = (c - 1) * CHUNKSZ + s;
            const bf16_t* base = &proj[(size_t)(row0 - CHUNKSZ + s) * LDP + 4096 + ch8];
            uint4 zz = make_uint4(0, 0, 0, 0);
            uint4 u3 = *(const uint4*)&base[0];
            uint4 u2 = (l >= 1) ? *(const uint4*)&base[-LDP]     : zz;
            uint4 u1 = (l >= 2) ? *(const uint4*)&base[-2 * LDP] : zz;
            uint4 u0 = (l >= 3) ? *(const uint4*)&base[-3 * LDP] : zz;
            float t3[8] = {bflo(u3.x), bfhi(u3.x), bflo(u3.y), bfhi(u3.y),
                           bflo(u3.z), bfhi(u3.z), bflo(u3.w), bfhi(u3.w)};
            float t2[8] = {bflo(u2.x), bfhi(u2.x), bflo(u2.y), bfhi(u2.y),
                           bflo(u2.z), bfhi(u2.z), bflo(u2.w), bfhi(u2.w)};
            float t1[8] = {bflo(u1.x), bfhi(u1.x), bflo(u1.y), bfhi(u1.y),
                           bflo(u1.z), bfhi(u1.z), bflo(u1.w), bfhi(u1.w)};
            float t0[8] = {bflo(u0.x), bfhi(u0.x), bflo(u0.y), bfhi(u0.y),
                           bflo(u0.z), bfhi(u0.z), bflo(u0.w), bfhi(u0.w)};
            #pragma unroll
            for (int j = 0; j < 8; ++j) {
                int ch = ch8 + j;
                float4 w = *(const float4*)&conv_w[(2048 + ch) * 4];
                float av = conv_b[2048 + ch];
                av = fmaf(w.x, t0[j], av);
                av = fmaf(w.y, t1[j], av);
                av = fmaf(w.z, t2[j], av);
                av = fmaf(w.w, t3[j], av);
                vout[j] = siluf_(av);
            }
        }
        #pragma unroll
        for (int j = 0; j < 8; ++j) BpT[ch8 + j][s] = f2bf(vout[j]);
    } else if (t < 192) {
        int s = t - 128;
        float v = bf2f(proj[(size_t)(row0 + s) * LDP + 4128 + h]) + bias;
        dtc[s] = softplusf_(v);
    } else {
        int s = t - 192;
        float w = 0.f;
        if (c > 0) {
            float v = bf2f(proj[(size_t)(row0 - CHUNKSZ + s) * LDP + 4128 + h]) + bias;
            w = softplusf_(v) * __expf(a * (float)(63 - s));   // fold decay_states
        }
        dtp[s] = w;
        // zero BpT pad rows 16..31 over s columns 0..63 (64 threads x 16 bf16)
        int idx = t - 192;
        int zr = 16 + (idx >> 2), zc = (idx & 3) * 16;
        uint4 zz = make_uint4(0, 0, 0, 0);
        *(uint4*)&BpT[zr][zc]     = zz;
        *(uint4*)&BpT[zr][zc + 8] = zz;
    }
    __syncthreads();

    // ---- phase B: scores -> sc_b (bf16); A2 rows ----
    {
        int l = t >> 2;
        int sbase = (t & 3) * 16;
        unsigned int pk[8];
        #pragma unroll
        for (int jj = 0; jj < 16; jj += 2) {
            float v0 = 0.f, v1 = 0.f;
            int s0 = sbase + jj, s1 = s0 + 1;
            if (s0 <= l) {
                float dot = 0.f;
                #pragma unroll
                for (int n = 0; n < 16; ++n) dot = fmaf(Cc[l][n], Bc[s0][n], dot);
                v0 = dot * __expf(a * (float)(l - s0));
                if (s0 == l) v0 += Dsk;
            }
            if (s1 <= l) {
                float dot = 0.f;
                #pragma unroll
                for (int n = 0; n < 16; ++n) dot = fmaf(Cc[l][n], Bc[s1][n], dot);
                v1 = dot * __expf(a * (float)(l - s1));
                if (s1 == l) v1 += Dsk;
            }
            pk[jj >> 1] = pack2(v0, v1);
        }
        uint4 u0 = {pk[0], pk[1], pk[2], pk[3]};
        uint4 u1 = {pk[4], pk[5], pk[6], pk[7]};
        *(uint4*)&sc_b[l][sbase]     = u0;
        *(uint4*)&sc_b[l][sbase + 8] = u1;
    }
    if (t < 64) {   // A2[t][n] = bf16(exp(a(t+1)) * Cc[t][n]); n>=16 zero
        float e = __expf(a * (float)(t + 1));
        unsigned int pk[8];
        #pragma unroll
        for (int n = 0; n < 16; n += 2) pk[n >> 1] = pack2(e * Cc[t][n], e * Cc[t][n + 1]);
        uint4 u0 = {pk[0], pk[1], pk[2], pk[3]};
        uint4 u1 = {pk[4], pk[5], pk[6], pk[7]};
        uint4 zz = make_uint4(0, 0, 0, 0);
        *(uint4*)&A2[t][0]  = u0;
        *(uint4*)&A2[t][8]  = u1;
        *(uint4*)&A2[t][16] = zz;
        *(uint4*)&A2[t][24] = zz;
    }

    // ---- phase C: prev conv -> xT -> Sp(MFMA) -> SpT; then cur conv -> xT ----
    {
        const int p = t;
        const int wave = t >> 6, lane = t & 63;
        const int r5 = lane & 31, hi = lane >> 5;
        const int xch = h * HEADDIM + p;          // x channel 0..2047
        const float4 w = *(const float4*)&conv_w[(size_t)xch * 4];
        const float cb = conv_b[xch];
        const int colp = 2048 + xch;              // proj column

        // C1: previous chunk conv * dtp -> xT[p][s]  (zeros when c == 0)
        if (c > 0) {
            const bf16_t* pr = &proj[(size_t)(row0 - CHUNKSZ) * LDP + colp];
            int l0 = (c - 1) * CHUNKSZ;
            float xm3 = (l0 >= 3) ? bf2f(pr[-3 * LDP]) : 0.f;
            float xm2 = (l0 >= 2) ? bf2f(pr[-2 * LDP]) : 0.f;
            float xm1 = (l0 >= 1) ? bf2f(pr[-LDP])     : 0.f;
            #pragma unroll
            for (int s0 = 0; s0 < 64; s0 += 8) {
                float xd[8];
                #pragma unroll
                for (int q = 0; q < 8; ++q) {
                    float xc = bf2f(pr[(size_t)(s0 + q) * LDP]);
                    float av = cb;
                    av = fmaf(w.x, xm3, av);
                    av = fmaf(w.y, xm2, av);
                    av = fmaf(w.z, xm1, av);
                    av = fmaf(w.w, xc, av);
                    xd[q] = siluf_(av) * dtp[s0 + q];
                    xm3 = xm2; xm2 = xm1; xm1 = xc;
                }
                uint4 u;
                u.x = pack2(xd[0], xd[1]); u.y = pack2(xd[2], xd[3]);
                u.z = pack2(xd[4], xd[5]); u.w = pack2(xd[6], xd[7]);
                *(uint4*)&xT[p][s0] = u;
            }
        } else {
            uint4 zz = make_uint4(0, 0, 0, 0);
            #pragma unroll
            for (int s0 = 0; s0 < 64; s0 += 8) *(uint4*)&xT[p][s0] = zz;
        }

        // C2: Sp[p][n] = sum_s xT[p][s] * BpT[n][s] via MFMA.
        {
            f32x16 sacc[2];
            #pragma unroll
            for (int rb = 0; rb < 2; ++rb)
                #pragma unroll
                for (int r = 0; r < 16; ++r) sacc[rb][r] = 0.f;
            #pragma unroll
            for (int ks = 0; ks < 4; ++ks) {
                bfrag bb = *(const bfrag*)&BpT[r5][ks * 16 + hi * 8];
                #pragma unroll
                for (int rb = 0; rb < 2; ++rb) {
                    bfrag aa = *(const bfrag*)
                        &xT[64 * wave + rb * 32 + r5][ks * 16 + hi * 8];
                    sacc[rb] = __builtin_amdgcn_mfma_f32_32x32x16_bf16(
                                   aa, bb, sacc[rb], 0, 0, 0);
                }
            }
            #pragma unroll
            for (int rb = 0; rb < 2; ++rb)
                #pragma unroll
                for (int reg = 0; reg < 16; ++reg) {
                    int pr_ = 64 * wave + rb * 32
                            + (reg & 3) + 8 * (reg >> 2) + 4 * hi;
                    SpT[pr_][r5] = f2bf(sacc[rb][reg]);   // n>=16 cols get 0
                }
        }

        // C3: current chunk conv * dtc -> xT[p][s] (overwrite; wave-local rows)
        {
            const bf16_t* pr = &proj[(size_t)row0 * LDP + colp];
            int l0 = c * CHUNKSZ;
            float xm3 = (l0 >= 3) ? bf2f(pr[-3 * LDP]) : 0.f;
            float xm2 = (l0 >= 2) ? bf2f(pr[-2 * LDP]) : 0.f;
            float xm1 = (l0 >= 1) ? bf2f(pr[-LDP])     : 0.f;
            #pragma unroll
            for (int s0 = 0; s0 < 64; s0 += 8) {
                float xd[8];
                #pragma unroll
                for (int q = 0; q < 8; ++q) {
                    float xc = bf2f(pr[(size_t)(s0 + q) * LDP]);
                    float av = cb;
                    av = fmaf(w.x, xm3, av);
                    av = fmaf(w.y, xm2, av);
                    av = fmaf(w.z, xm1, av);
                    av = fmaf(w.w, xc, av);
                    xd[q] = siluf_(av) * dtc[s0 + q];
                    xm3 = xm2; xm2 = xm1; xm1 = xc;
                }
                uint4 u;
                u.x = pack2(xd[0], xd[1]); u.y = pack2(xd[2], xd[3]);
                u.z = pack2(xd[4], xd[5]); u.w = pack2(xd[6], xd[7]);
                *(uint4*)&xT[p][s0] = u;
            }
        }
    }
    __syncthreads();

    // ---- phase D: MFMA + gated coalesced epilogue ----
    {
        const int wave = t >> 6, lane = t & 63;
        const int quad = lane >> 4, fr = lane & 15;
        f32x4 acc[4][4];
        #pragma unroll
        for (int i = 0; i < 4; ++i)
            #pragma unroll
            for (int j = 0; j < 4; ++j) {
                f32x4 z = {0.f, 0.f, 0.f, 0.f};
                acc[i][j] = z;
            }
        #pragma unroll
        for (int kk = 0; kk < 2; ++kk) {
            bfrag af[4], bfr[4];
            #pragma unroll
            for (int i = 0; i < 4; ++i)
                af[i] = *(const bfrag*)&sc_b[16 * i + fr][32 * kk + quad * 8];
            #pragma unroll
            for (int j = 0; j < 4; ++j)
                bfr[j] = *(const bfrag*)&xT[64 * wave + 16 * j + fr][32 * kk + quad * 8];
            #pragma unroll
            for (int i = 0; i < 4; ++i)
                #pragma unroll
                for (int j = 0; j < 4; ++j)
                    acc[i][j] = __builtin_amdgcn_mfma_f32_16x16x32_bf16(
                                    af[i], bfr[j], acc[i][j], 0, 0, 0);
        }
        {   // off-chunk term: K=32 over n (16 real + 16 zero)
            bfrag af[4], bfr[4];
            #pragma unroll
            for (int i = 0; i < 4; ++i)
                af[i] = *(const bfrag*)&A2[16 * i + fr][quad * 8];
            #pragma unroll
            for (int j = 0; j < 4; ++j)
                bfr[j] = *(const bfrag*)&SpT[64 * wave + 16 * j + fr][quad * 8];
            #pragma unroll
            for (int i = 0; i < 4; ++i)
                #pragma unroll
                for (int j = 0; j < 4; ++j)
                    acc[i][j] = __builtin_amdgcn_mfma_f32_16x16x32_bf16(
                                    af[i], bfr[j], acc[i][j], 0, 0, 0);
        }
        __syncthreads();                    // all MFMA reads of xT done
        bf16_t* buf = &xT[0][0];            // reuse as Y[64][264]
        #pragma unroll
        for (int i = 0; i < 4; ++i)
            #pragma unroll
            for (int j = 0; j < 4; ++j) {
                int pc = 64 * wave + 16 * j + fr;
                #pragma unroll
                for (int r = 0; r < 4; ++r) {
                    int l = 16 * i + quad * 4 + r;
                    buf[l * 264 + pc] = f2bf(acc[i][j][r]);
                }
            }
        __syncthreads();
        bf16_t* ybase = &ybuf[(size_t)row0 * DINNER + h * HEADDIM];
        const bf16_t* zbase = &proj[(size_t)row0 * LDP + h * HEADDIM];
        #pragma unroll
        for (int k = 0; k < 8; ++k) {
            int id = k * 256 + t;
            int l = id >> 5, ch = id & 31;
            uint4 yv = *(const uint4*)&buf[l * 264 + ch * 8];
            uint4 zv = *(const uint4*)&zbase[(size_t)l * LDP + ch * 8];
            float ya[8] = {bflo(yv.x), bfhi(yv.x), bflo(yv.y), bfhi(yv.y),
                           bflo(yv.z), bfhi(yv.z), bflo(yv.w), bfhi(yv.w)};
            float za[8] = {bflo(zv.x), bfhi(zv.x), bflo(zv.y), bfhi(zv.y),
                           bflo(zv.z), bfhi(zv.z), bflo(zv.w), bfhi(zv.w)};
            float g[8];
            float ss = 0.f;
            #pragma unroll
            for (int j = 0; j < 8; ++j) {
                float gv = ya[j] * siluf_(za[j]);
                g[j] = gv;
                ss = fmaf(gv, gv, ss);
            }
            uint4 o;
            o.x = pack2(g[0], g[1]); o.y = pack2(g[2], g[3]);
            o.z = pack2(g[4], g[5]); o.w = pack2(g[6], g[7]);
            *(uint4*)&ybase[(size_t)l * DINNER + ch * 8] = o;
            #pragma unroll
            for (int off = 16; off >= 1; off >>= 1) ss += __shfl_xor(ss, off, 32);
            if ((t & 31) == 0) atomicAdd(&rowsum[row0 + l], ss);
        }
    }
}

// ---------------------------------------------------------------------------
extern "C" void kernel_launch(void* const* d_in, const int* in_sizes, int n_in,
                              void* d_out, int out_size, void* d_ws, size_t ws_size,
                              hipStream_t stream)
{
    const float* input   = (const float*)d_in[0];
    const float* W_in    = (const float*)d_in[1];
    const float* conv_w  = (const float*)d_in[2];
    const float* conv_b  = (const float*)d_in[3];
    const float* dt_bias = (const float*)d_in[4];
    const float* log_A   = (const float*)d_in[5];
    const float* D_skip  = (const float*)d_in[6];
    const float* norm_w  = (const float*)d_in[7];
    const float* W_out   = (const float*)d_in[8];
    float* out = (float*)d_out;

    // workspace: proj(138.4MB, stride 4224) | region1 (68.2MB) | Wb2 | rowsum
    // region1: phase-1 = Ab(33.5)+Wb1(8.9, 4352 rows); phase-2 = ybuf (67.1MB)
    bf16_t* proj  = (bf16_t*)d_ws;
    bf16_t* region1 = proj + (size_t)ROWS * LDP;
    bf16_t* Wb2   = region1 + (size_t)ROWS * CONVDIM;
    float*  rowsum = (float*)(Wb2 + (size_t)DMODEL * DINNER);
    bf16_t* Ab    = region1;                     // alias (phase 1 only)
    bf16_t* Wb1   = Ab + (size_t)ROWS * DMODEL;  // alias (phase 1 only)
    bf16_t* ybuf  = region1;                     // alias (phase 2)

    size_t need = (size_t)ROWS * LDP * 2 + (size_t)ROWS * CONVDIM * 2
                + (size_t)DMODEL * DINNER * 2 + (size_t)ROWS * 4;
    if (ws_size < need) {
        hipMemsetAsync(d_out, 0, (size_t)out_size * sizeof(float), stream);
        return;
    }

    // 0) bf16 conversions (+ norm_w folded into Wb2); zero rowsum accumulator
    cvt_f32_bf16<<<(ROWS * DMODEL / 8 + 255) / 256, 256, 0, stream>>>(
        input, Ab, ROWS * DMODEL / 8);
    cvt_pad_w1<<<(NPADW * DMODEL / 4 + 255) / 256, 256, 0, stream>>>(W_in, Wb1);
    cvt_w2<<<(DMODEL * DINNER / 4 + 255) / 256, 256, 0, stream>>>(W_out, norm_w, Wb2);
    hipMemsetAsync(rowsum, 0, (size_t)ROWS * sizeof(float), stream);

    // 1) proj = input @ W_in^T  (barrier-light + conflict-free 16x16 frags)
    dim3 g1(NPADW / 256, ROWS / 256);            // 17 x 64 (nwg%8==0)
    gemm_g1<<<g1, 512, 0, stream>>>(Ab, Wb1, proj, nullptr,
                                    LDP, DMODEL, DMODEL, DMODEL, LDP);
    // 2) fused conv+SSD+gate -> ybuf (gated), rowsum = per-row sum(g^2)
    dim3 gs(NCHUNK, NHEADS, BATCH);
    ssd_fused<<<gs, 256, 0, stream>>>(proj, conv_w, conv_b, dt_bias,
                                      log_A, D_skip, ybuf, rowsum);
    // 3) out = g @ (W_out*norm_w)^T * rsqrt(rowsum/D+eps)  (N=1024, K=2048)
    dim3 g2(DMODEL / 256, ROWS / 256);           // 4 x 64 (nwg%8==0)
    gemm_g2<<<g2, 512, 0, stream>>>(ybuf, Wb2, out, rowsum,
                                    DMODEL, DINNER, DINNER, DINNER, DMODEL);
}